// Round 2
// baseline (269.806 us; speedup 1.0000x reference)
//
#include <hip/hip_runtime.h>
#include <hip/hip_bf16.h>
#include <cstdint>
#include <math.h>

// Problem constants
#define T_  4
#define B_  32
#define C_  384
#define HF_ 1536
#define HW_ 196
#define E_  8
#define N_  128
#define REC_CAP 16384
#define NPAIR 256          // 2*N pairs
#define NGT  50176         // max (pair,pos) tasks per expert
#define LCAP 64

#define LIFB (B_ * C_)        // 12288
#define TRB  (E_ * 12 * 24)   // 2304 transpose tiles
#define PRB  48

// ---------------------------------------------------------------------------
// K1: LIF spike counts + per-element expert "level" (u8) + BN-const folding +
//     w1 transpose->bf16 + rowmax partials
// level(x) = #{e : x/tau_e - 1 >= 0}; spike for expert e  <=>  level > e.
// Exact via te[e] = min{y : y/tau_e - 1 >= 0} (division is monotonic).
// ---------------------------------------------------------------------------
__global__ __launch_bounds__(256) void k_lifprep(
    const float* __restrict__ x, float* __restrict__ cnt,
    unsigned char* __restrict__ levels,
    const float* __restrict__ w1, __hip_bfloat16* __restrict__ w1t,
    const float* b1, const float* g1, const float* be1,
    const float* m1, const float* v1,
    const float* b2, const float* g2, const float* be2,
    const float* m2, const float* v2,
    const float* taus,
    float* A, float* Bc, float* const2, float* inv2v,
    float* rowmaxp, int* header) {
  __shared__ float tile[64][33];
  __shared__ int c4[T_];
  int blk = blockIdx.x;
  int tid = threadIdx.x;

  if (blk < LIFB) {
    // ---- LIF + levels ----
    if (tid < T_) c4[tid] = 0;
    __syncthreads();
    // effective thresholds te[e] (same division semantics as reference path)
    float te[E_];
    #pragma unroll
    for (int e2 = 0; e2 < E_; ++e2) {
      float t = taus[e2];
      float y = t;                      // y/t == 1.0 exactly -> satisfies
      #pragma unroll
      for (int it = 0; it < 4; ++it) {
        float cnd = __uint_as_float(__float_as_uint(y) - 1u);
        if (cnd / t - 1.0f >= 0.0f) y = cnd; else break;
      }
      te[e2] = y;
    }
    int bc = blk;
    bool act = tid < HW_;
    float v = 0.f;
    size_t base = (size_t)bc * HW_ + (act ? tid : 0);
    #pragma unroll
    for (int t = 0; t < T_; ++t) {
      float xv = act ? x[base + (size_t)t * B_ * C_ * HW_] : -1e30f;
      v = v + (xv - v) * 0.5f;                 // tau=2.0
      bool sp = (v - 1.0f >= 0.0f);
      if (sp) v = 0.f;
      unsigned long long m = __ballot(act && sp);
      if ((tid & 63) == 0) atomicAdd(&c4[t], __popcll(m));
      if (act) {
        int lvl = 0;
        #pragma unroll
        for (int e2 = 0; e2 < E_; ++e2) lvl += (xv >= te[e2]) ? 1 : 0;
        levels[(size_t)t * B_ * C_ * HW_ + base] = (unsigned char)lvl;
      }
    }
    __syncthreads();
    if (tid < T_) cnt[(size_t)tid * B_ * C_ + bc] = (float)c4[tid];
  } else if (blk < LIFB + TRB) {
    // ---- transpose w1 -> bf16 w1t + rowmax partials ----
    int rem = blk - LIFB;
    int e = rem / 288, r2 = rem % 288;
    int ct = r2 / 24, ot = r2 % 24;
    int c0 = ct * 32, o0 = ot * 64;
    int cl = tid & 31, olb = tid >> 5;
    #pragma unroll
    for (int it = 0; it < 8; ++it) {
      int ol = olb + it * 8;
      tile[ol][cl] = w1[(size_t)(e * HF_ + o0 + ol) * C_ + c0 + cl];
    }
    __syncthreads();
    int ol2 = tid & 63, clb = tid >> 6;
    #pragma unroll
    for (int it = 0; it < 8; ++it) {
      int cl2 = clb + it * 4;
      w1t[(size_t)(e * C_ + c0 + cl2) * HF_ + o0 + ol2] =
          __float2bfloat16(tile[ol2][cl2]);
    }
    // per-(c, ot) max |bf16(w1)| over this tile's 64 outputs (race-free partials)
    if (tid < 32) {
      float m = 0.f;
      for (int ol = 0; ol < 64; ++ol) {
        float bv = __bfloat162float(__float2bfloat16(tile[ol][tid]));
        m = fmaxf(m, fabsf(bv));
      }
      rowmaxp[(size_t)(e * C_ + c0 + tid) * 24 + ot] = m;
    }
  } else {
    // ---- prep ----
    int idx = (blk - LIFB - TRB) * 256 + tid;
    if (idx < 64) header[idx] = 0;
    if (idx < E_ * HF_) {
      int e = idx / HF_;
      float inv = g1[idx] / sqrtf(v1[idx] + 1e-5f);
      float sh  = be1[idx] - m1[idx] * inv;
      A[idx]  = inv;
      Bc[idx] = inv * b1[idx] + sh - taus[e];
    }
    if (idx < E_ * C_) {
      float inv = g2[idx] / sqrtf(v2[idx] + 1e-5f);
      const2[idx] = b2[idx] * inv + (be2[idx] - m2[idx] * inv);
      inv2v[idx]  = inv;
    }
  }
}

// ---------------------------------------------------------------------------
// K2: router (blocks 0..N-1) + rowmax reduce (N..N+11) + thrmin (N+12)
// ---------------------------------------------------------------------------
__global__ __launch_bounds__(256) void k_router(
    const float* __restrict__ cnt, const float* __restrict__ rw,
    const float* rb, const float* rg, const float* rbeta,
    const float* rmean, const float* rvar,
    const float* __restrict__ const2,
    const float* __restrict__ rowmaxp, float* __restrict__ rowmax,
    const float* __restrict__ A, const float* __restrict__ Bc,
    float* __restrict__ thrmin,
    int* sel_e, float* sel_g, float* gsum, float* K,
    float* f_acc, float* p_acc) {
  __shared__ float sc[C_ + 256 + E_];
  __shared__ int s_i1, s_i2;
  __shared__ float s_g1, s_g2;
  int bid = blockIdx.x, tid = threadIdx.x;

  if (bid < N_) {
    int n = bid;
    float* part = sc + C_;
    float* lg = part + 256;
    for (int c = tid; c < C_; c += 256) sc[c] = cnt[(size_t)n * C_ + c];
    __syncthreads();
    {
      int e = tid >> 5, sub = tid & 31;
      float d = 0.f;
      for (int c = sub; c < C_; c += 32) d += rw[e * C_ + c] * sc[c];
      part[tid] = d;
    }
    __syncthreads();
    if (tid < E_) {
      float dot = 0.f;
      #pragma unroll
      for (int j = 0; j < 32; ++j) dot += part[tid * 32 + j];
      float inv = rg[tid] / sqrtf(rvar[tid] + 1e-5f);
      lg[tid] = (dot * (1.0f / HW_) + rb[tid]) * inv +
                (rbeta[tid] - rmean[tid] * inv);
    }
    __syncthreads();
    if (tid == 0) {
      float m = lg[0];
      for (int e = 1; e < E_; ++e) m = fmaxf(m, lg[e]);
      float pr[E_]; float s = 0.f;
      for (int e = 0; e < E_; ++e) { pr[e] = expf(lg[e] - m); s += pr[e]; }
      float invs = 1.0f / s;
      for (int e = 0; e < E_; ++e) pr[e] *= invs;
      int i1 = 0;
      for (int e = 1; e < E_; ++e) if (pr[e] > pr[i1]) i1 = e;
      int i2 = (i1 == 0) ? 1 : 0;
      for (int e = 0; e < E_; ++e) if (e != i1 && pr[e] > pr[i2]) i2 = e;
      float w = pr[i1] + pr[i2];
      float ga = pr[i1] / w, gb = pr[i2] / w;
      sel_e[2 * n] = i1; sel_e[2 * n + 1] = i2;
      sel_g[2 * n] = ga; sel_g[2 * n + 1] = gb;
      gsum[n] = ga + gb;
      s_i1 = i1; s_i2 = i2; s_g1 = ga; s_g2 = gb;
      atomicAdd(&f_acc[i1], 1.0f);
      atomicAdd(&f_acc[i2], 1.0f);
      for (int e = 0; e < E_; ++e) atomicAdd(&p_acc[e], pr[e]);
    }
    __syncthreads();
    int i1 = s_i1, i2 = s_i2; float ga = s_g1, gb = s_g2;
    for (int c = tid; c < C_; c += 256)
      K[(size_t)n * C_ + c] =
          ga * const2[i1 * C_ + c] + gb * const2[i2 * C_ + c];
  } else if (bid < N_ + 12) {
    // reduce rowmax partials: 3072 (e,c) entries
    int idx = (bid - N_) * 256 + tid;
    if (idx < E_ * C_) {
      float m = 0.f;
      #pragma unroll
      for (int t = 0; t < 24; ++t) m = fmaxf(m, rowmaxp[(size_t)idx * 24 + t]);
      rowmax[idx] = m;
    }
  } else {
    // thrmin[e] = min_o ( A!=0 ? -B/|A| : (B>=0 ? -inf : +inf) )
    float* red = sc;
    for (int e = 0; e < E_; ++e) {
      float m = INFINITY;
      for (int o = tid; o < HF_; o += 256) {
        float a = A[e * HF_ + o], b = Bc[e * HF_ + o];
        float thr = (a != 0.0f) ? (-b / fabsf(a))
                                : ((b >= 0.0f) ? -INFINITY : INFINITY);
        m = fminf(m, thr);
      }
      red[tid] = m;
      __syncthreads();
      for (int s = 128; s > 0; s >>= 1) {
        if (tid < s) red[tid] = fminf(red[tid], red[tid + s]);
        __syncthreads();
      }
      if (tid == 0) thrmin[e] = red[0];
      __syncthreads();
    }
  }
}

// ---------------------------------------------------------------------------
// K3: one block per pair (uniform expert). Stage levels[n] (75 KB) to LDS,
// build spike lists for 196 positions, certified bound-prune, compact
// survivors into PER-EXPERT queues (entry = tw | nnz<<20).
// ---------------------------------------------------------------------------
__global__ __launch_bounds__(256) void k_lists(
    const unsigned char* __restrict__ levels, const int* __restrict__ sel_e,
    const float* __restrict__ rowmax, const float* __restrict__ thrmin,
    unsigned short* __restrict__ list16,
    int* __restrict__ queue, int* __restrict__ qcount) {
  __shared__ unsigned char xs8[C_ * HW_];   // 75264 B
  __shared__ float rmx[C_];
  int bid = blockIdx.x, tid = threadIdx.x;
  int lane = tid & 63, wave = tid >> 6;
  int pair = bid, n = bid >> 1;
  int e = sel_e[pair];
  unsigned long long lmask = (1ull << lane) - 1ull;

  {
    const uint4* src = (const uint4*)(levels + (size_t)n * (C_ * HW_));
    uint4* dst = (uint4*)xs8;
    for (int i = tid; i < (C_ * HW_) / 16; i += 256) dst[i] = src[i];
  }
  for (int c = tid; c < C_; c += 256) rmx[c] = rowmax[e * C_ + c];
  __syncthreads();

  float thr = thrmin[e] - 1e-4f;
  for (int pos = wave; pos < HW_; pos += 4) {
    unsigned long long masks[6];
    int nnz = 0;
    float myb = 0.f;
    #pragma unroll
    for (int cb = 0; cb < 6; ++cb) {
      int c = cb * 64 + lane;
      bool sp = (int)xs8[c * HW_ + pos] > e;
      unsigned long long m = __ballot(sp);
      masks[cb] = m;
      if (sp) myb += rmx[c];
      nnz += __popcll(m);
    }
    // wave-sum the bound
    #pragma unroll
    for (int off = 1; off < 64; off <<= 1) myb += __shfl_xor(myb, off, 64);
    if (myb >= thr) {
      int tw = pair * HW_ + pos;
      size_t lbase = (size_t)tw * LCAP;
      int cum = 0;
      #pragma unroll
      for (int cb = 0; cb < 6; ++cb) {
        unsigned long long m = masks[cb];
        bool sp2 = (m >> lane) & 1ull;
        int p2 = cum + __popcll(m & lmask);
        if (sp2 && p2 < LCAP) list16[lbase + p2] = (unsigned short)(cb * 64 + lane);
        cum += __popcll(m);
      }
      if (lane == 0) {
        int nv = nnz < LCAP ? nnz : LCAP;
        int qi = atomicAdd(&qcount[e], 1);
        queue[e * NGT + qi] = tw | (nv << 20);
      }
    }
  }
}

// ---------------------------------------------------------------------------
// K3b: streaming combine out = gsum[n]*x + K[n,c]  (thread per float4, coalesced)
// ---------------------------------------------------------------------------
__global__ __launch_bounds__(256) void k_combine(
    const float* __restrict__ x, const float* __restrict__ gsum,
    const float* __restrict__ K, float* __restrict__ out) {
  int idx = blockIdx.x * 256 + threadIdx.x;     // over N*C*49 float4s
  int nc = idx / 49;                            // (n,c) row
  float g = gsum[nc / C_];
  float kc = K[nc];
  float4 v = ((const float4*)x)[idx];
  v.x = g * v.x + kc;
  v.y = g * v.y + kc;
  v.z = g * v.z + kc;
  v.w = g * v.w + kc;
  ((float4*)out)[idx] = v;
}

// ---------------------------------------------------------------------------
// K4: gather — expert-major sweep over per-expert queues (L2-resident w1t
// slice per expert). One wave per surviving task; 3 passes of 8 outputs/lane.
// ---------------------------------------------------------------------------
__global__ __launch_bounds__(256, 4) void k_gather(
    const __hip_bfloat16* __restrict__ w1t,
    const float* __restrict__ A, const float* __restrict__ Bc,
    const int* __restrict__ queue, const int* __restrict__ qcount,
    const unsigned short* __restrict__ list16,
    int* __restrict__ rec, int* __restrict__ rec_count) {
  int wid = blockIdx.x * 4 + (threadIdx.x >> 6);
  int lane = threadIdx.x & 63;
  int nwaves = gridDim.x * 4;

  for (int e = 0; e < E_; ++e) {
    int nq = qcount[e];
    const int* qe = queue + e * NGT;
    const uint4* wb = (const uint4*)(w1t + (size_t)e * C_ * HF_);  // 192 uint4/row
    for (int qi = wid; qi < nq; qi += nwaves) {
      int ent = qe[qi];
      int tw = ent & 0xFFFFF;
      int nnz = ent >> 20;
      int pair = tw / HW_, pos = tw - pair * HW_;
      int lv = (int)list16[(size_t)tw * LCAP + lane];

      #pragma unroll
      for (int pass = 0; pass < 3; ++pass) {
        const uint4* wbp = wb + pass * 64 + lane;
        float acc[8];
        #pragma unroll
        for (int q = 0; q < 8; ++q) acc[q] = 0.f;
        int j = 0;
        for (; j + 4 <= nnz; j += 4) {
          int c0 = __shfl(lv, j + 0);
          int c1 = __shfl(lv, j + 1);
          int c2 = __shfl(lv, j + 2);
          int c3 = __shfl(lv, j + 3);
          uint4 a = wbp[c0 * 192];
          uint4 b = wbp[c1 * 192];
          uint4 c = wbp[c2 * 192];
          uint4 d = wbp[c3 * 192];
          uint32_t ua[4] = {a.x, a.y, a.z, a.w};
          uint32_t ub[4] = {b.x, b.y, b.z, b.w};
          uint32_t uc[4] = {c.x, c.y, c.z, c.w};
          uint32_t ud[4] = {d.x, d.y, d.z, d.w};
          #pragma unroll
          for (int q = 0; q < 4; ++q) {
            acc[2 * q]     += __uint_as_float(ua[q] << 16) + __uint_as_float(ub[q] << 16) +
                              __uint_as_float(uc[q] << 16) + __uint_as_float(ud[q] << 16);
            acc[2 * q + 1] += __uint_as_float(ua[q] & 0xffff0000u) + __uint_as_float(ub[q] & 0xffff0000u) +
                              __uint_as_float(uc[q] & 0xffff0000u) + __uint_as_float(ud[q] & 0xffff0000u);
          }
        }
        for (; j < nnz; ++j) {
          int c0 = __shfl(lv, j);
          uint4 a = wbp[c0 * 192];
          uint32_t ua[4] = {a.x, a.y, a.z, a.w};
          #pragma unroll
          for (int q = 0; q < 4; ++q) {
            acc[2 * q]     += __uint_as_float(ua[q] << 16);
            acc[2 * q + 1] += __uint_as_float(ua[q] & 0xffff0000u);
          }
        }
        // threshold for my 8 outputs: o = (pass*64+lane)*8 + q
        int k2 = (pass * 64 + lane) * 2;
        float4 Av0 = ((const float4*)(A + e * HF_))[k2];
        float4 Av1 = ((const float4*)(A + e * HF_))[k2 + 1];
        float4 Bv0 = ((const float4*)(Bc + e * HF_))[k2];
        float4 Bv1 = ((const float4*)(Bc + e * HF_))[k2 + 1];
        float av[8] = {Av0.x, Av0.y, Av0.z, Av0.w, Av1.x, Av1.y, Av1.z, Av1.w};
        float bv[8] = {Bv0.x, Bv0.y, Bv0.z, Bv0.w, Bv1.x, Bv1.y, Bv1.z, Bv1.w};
        #pragma unroll
        for (int q = 0; q < 8; ++q) {
          if (av[q] * acc[q] + bv[q] >= 0.0f) {     // layer-2 spike (rare)
            int ridx = atomicAdd(rec_count, 1);
            if (ridx < REC_CAP) {
              rec[ridx * 3 + 0] = pair;
              rec[ridx * 3 + 1] = pos;
              rec[ridx * 3 + 2] = (pass * 64 + lane) * 8 + q;
            }
          }
        }
      }
    }
  }
}

// ---------------------------------------------------------------------------
// K5: apply rare records; write aux
// ---------------------------------------------------------------------------
__global__ void k_apply(const int* __restrict__ rec, const int* __restrict__ rec_count,
                        const int* __restrict__ sel_e, const float* __restrict__ sel_g,
                        const float* __restrict__ inv2v, const float* __restrict__ w2,
                        const float* f_acc, const float* p_acc,
                        float* __restrict__ out, float* aux_out) {
  int nrec = *rec_count;
  if (nrec > REC_CAP) nrec = REC_CAP;
  for (int r = blockIdx.x; r < nrec; r += gridDim.x) {
    int pair = rec[r * 3], pos = rec[r * 3 + 1], o = rec[r * 3 + 2];
    int n = pair >> 1;
    int e = sel_e[pair];
    float g = sel_g[pair];
    for (int c = threadIdx.x; c < C_; c += blockDim.x) {
      float wv = w2[(size_t)(e * C_ + c) * HF_ + o];
      atomicAdd(&out[(size_t)(n * C_ + c) * HW_ + pos],
                g * inv2v[e * C_ + c] * wv);
    }
  }
  if (blockIdx.x == 0 && threadIdx.x == 0) {
    float s = 0.f;
    for (int e = 0; e < E_; ++e)
      s += (f_acc[e] * (1.0f / N_)) * (p_acc[e] * (1.0f / N_));
    *aux_out = 0.01f * E_ * s;
  }
}

// ---------------------------------------------------------------------------
// Workspace layout (bytes), total ~28.1 MB
// ---------------------------------------------------------------------------
extern "C" void kernel_launch(void* const* d_in, const int* in_sizes, int n_in,
                              void* d_out, int out_size, void* d_ws, size_t ws_size,
                              hipStream_t stream) {
  const float* x       = (const float*)d_in[0];
  const float* rw      = (const float*)d_in[1];
  const float* rb      = (const float*)d_in[2];
  const float* r_gamma = (const float*)d_in[3];
  const float* r_beta  = (const float*)d_in[4];
  const float* r_mean  = (const float*)d_in[5];
  const float* r_var   = (const float*)d_in[6];
  const float* w1      = (const float*)d_in[7];
  const float* b1      = (const float*)d_in[8];
  const float* g1      = (const float*)d_in[9];
  const float* be1     = (const float*)d_in[10];
  const float* m1      = (const float*)d_in[11];
  const float* v1      = (const float*)d_in[12];
  const float* w2      = (const float*)d_in[13];
  const float* b2      = (const float*)d_in[14];
  const float* g2      = (const float*)d_in[15];
  const float* be2     = (const float*)d_in[16];
  const float* m2      = (const float*)d_in[17];
  const float* v2      = (const float*)d_in[18];
  const float* taus    = (const float*)d_in[19];
  float* out = (float*)d_out;

  char* ws = (char*)d_ws;
  int*   header = (int*)ws;                 // [0]=rec_count, [32..39]=qcount[8]
  float* f_acc  = (float*)ws + 8;
  float* p_acc  = (float*)ws + 16;
  int*   qcount = header + 32;
  float* cnt    = (float*)(ws + 256);       // 196608 B
  int*   sel_e  = (int*)(ws + 196864);
  float* sel_g  = (float*)(ws + 197888);
  float* gsum   = (float*)(ws + 198912);
  float* K      = (float*)(ws + 199424);    // 196608 B
  float* A      = (float*)(ws + 396032);
  float* Bc     = (float*)(ws + 445184);
  float* const2 = (float*)(ws + 494336);
  float* inv2v  = (float*)(ws + 506624);
  int*   rec    = (int*)(ws + 518912);      // 196608 B
  __hip_bfloat16* w1t = (__hip_bfloat16*)(ws + 715520);     // 9437184 B
  int*   queue  = (int*)(ws + 10152704);    // 8 * 50176 * 4 = 1605632 B
  unsigned short* list16 = (unsigned short*)(ws + 11758336); // 6422528 B
  unsigned char* levels  = (unsigned char*)(ws + 18180864);  // 9633792 B
  float* rowmaxp = (float*)(ws + 27814656); // 294912 B
  float* rowmax  = (float*)(ws + 28109568); // 12288 B
  float* thrmin  = (float*)(ws + 28121856); // 32 B

  k_lifprep<<<LIFB + TRB + PRB, 256, 0, stream>>>(
      x, cnt, levels, w1, w1t, b1, g1, be1, m1, v1, b2, g2, be2, m2, v2, taus,
      A, Bc, const2, inv2v, rowmaxp, header);
  k_router<<<N_ + 13, 256, 0, stream>>>(
      cnt, rw, rb, r_gamma, r_beta, r_mean, r_var, const2,
      rowmaxp, rowmax, A, Bc, thrmin,
      sel_e, sel_g, gsum, K, f_acc, p_acc);
  k_lists<<<NPAIR, 256, 0, stream>>>(
      levels, sel_e, rowmax, thrmin, list16, queue, qcount);
  k_combine<<<(N_ * C_ * 49) / 256, 256, 0, stream>>>(x, gsum, K, out);
  k_gather<<<2048, 256, 0, stream>>>(
      w1t, A, Bc, queue, qcount, list16, rec, header);
  k_apply<<<64, 256, 0, stream>>>(
      rec, header, sel_e, sel_g, inv2v, w2, f_acc, p_acc,
      out, out + (out_size - 1));
}

// Round 3
// 238.974 us; speedup vs baseline: 1.1290x; 1.1290x over previous
//
#include <hip/hip_runtime.h>
#include <hip/hip_bf16.h>
#include <cstdint>
#include <math.h>

// Problem constants
#define T_  4
#define B_  32
#define C_  384
#define HF_ 1536
#define HW_ 196
#define E_  8
#define N_  128
#define REC_CAP 16384
#define NPAIR 256          // 2*N pairs
#define NGT  50176         // max (pair,pos) tasks
#define LCAP 64

#define LIFB (B_ * C_)        // 12288
#define TRB  (E_ * 12 * 24)   // 2304 transpose tiles
#define PRB  48

// ---------------------------------------------------------------------------
// K1: LIF spike counts + per-element expert "level" (u8) + BN-const folding +
//     w1 transpose->bf16 + rowmax partials
// level(x) = #{e : x/tau_e - 1 >= 0}; spike for expert e  <=>  level > e.
// Exact via te[e] = min{y : y/tau_e - 1 >= 0} (division is monotonic);
// te computed once per block by 8 threads (LDS broadcast).
// ---------------------------------------------------------------------------
__global__ __launch_bounds__(256) void k_lifprep(
    const float* __restrict__ x, float* __restrict__ cnt,
    unsigned char* __restrict__ levels,
    const float* __restrict__ w1, __hip_bfloat16* __restrict__ w1t,
    const float* b1, const float* g1, const float* be1,
    const float* m1, const float* v1,
    const float* b2, const float* g2, const float* be2,
    const float* m2, const float* v2,
    const float* taus,
    float* A, float* Bc, float* const2, float* inv2v,
    float* rowmaxp, int* header) {
  __shared__ float tile[64][33];
  __shared__ int c4[T_];
  __shared__ float s_te[E_];
  int blk = blockIdx.x;
  int tid = threadIdx.x;

  if (blk < LIFB) {
    // ---- LIF + levels ----
    if (tid < T_) c4[tid] = 0;
    if (tid < E_) {
      float t = taus[tid];
      float y = t;                      // y/t == 1.0 exactly -> satisfies
      #pragma unroll
      for (int it = 0; it < 4; ++it) {
        float cnd = __uint_as_float(__float_as_uint(y) - 1u);
        if (cnd / t - 1.0f >= 0.0f) y = cnd; else break;
      }
      s_te[tid] = y;
    }
    __syncthreads();
    int bc = blk;
    bool act = tid < HW_;
    float v = 0.f;
    size_t base = (size_t)bc * HW_ + (act ? tid : 0);
    #pragma unroll
    for (int t = 0; t < T_; ++t) {
      float xv = act ? x[base + (size_t)t * B_ * C_ * HW_] : -1e30f;
      v = v + (xv - v) * 0.5f;                 // tau=2.0
      bool sp = (v - 1.0f >= 0.0f);
      if (sp) v = 0.f;
      unsigned long long m = __ballot(act && sp);
      if ((tid & 63) == 0) atomicAdd(&c4[t], __popcll(m));
      if (act) {
        int lvl = 0;
        #pragma unroll
        for (int e2 = 0; e2 < E_; ++e2) lvl += (xv >= s_te[e2]) ? 1 : 0;
        levels[(size_t)t * B_ * C_ * HW_ + base] = (unsigned char)lvl;
      }
    }
    __syncthreads();
    if (tid < T_) cnt[(size_t)tid * B_ * C_ + bc] = (float)c4[tid];
  } else if (blk < LIFB + TRB) {
    // ---- transpose w1 -> bf16 w1t + rowmax partials ----
    int rem = blk - LIFB;
    int e = rem / 288, r2 = rem % 288;
    int ct = r2 / 24, ot = r2 % 24;
    int c0 = ct * 32, o0 = ot * 64;
    int cl = tid & 31, olb = tid >> 5;
    #pragma unroll
    for (int it = 0; it < 8; ++it) {
      int ol = olb + it * 8;
      tile[ol][cl] = w1[(size_t)(e * HF_ + o0 + ol) * C_ + c0 + cl];
    }
    __syncthreads();
    int ol2 = tid & 63, clb = tid >> 6;
    #pragma unroll
    for (int it = 0; it < 8; ++it) {
      int cl2 = clb + it * 4;
      w1t[(size_t)(e * C_ + c0 + cl2) * HF_ + o0 + ol2] =
          __float2bfloat16(tile[ol2][cl2]);
    }
    // per-(c, ot) max |bf16(w1)| over this tile's 64 outputs (race-free partials)
    if (tid < 32) {
      float m = 0.f;
      for (int ol = 0; ol < 64; ++ol) {
        float bv = __bfloat162float(__float2bfloat16(tile[ol][tid]));
        m = fmaxf(m, fabsf(bv));
      }
      rowmaxp[(size_t)(e * C_ + c0 + tid) * 24 + ot] = m;
    }
  } else {
    // ---- prep ----
    int idx = (blk - LIFB - TRB) * 256 + tid;
    if (idx < 64) header[idx] = 0;
    if (idx < E_ * HF_) {
      int e = idx / HF_;
      float inv = g1[idx] / sqrtf(v1[idx] + 1e-5f);
      float sh  = be1[idx] - m1[idx] * inv;
      A[idx]  = inv;
      Bc[idx] = inv * b1[idx] + sh - taus[e];
    }
    if (idx < E_ * C_) {
      float inv = g2[idx] / sqrtf(v2[idx] + 1e-5f);
      const2[idx] = b2[idx] * inv + (be2[idx] - m2[idx] * inv);
      inv2v[idx]  = inv;
    }
  }
}

// ---------------------------------------------------------------------------
// K2: router (blocks 0..N-1) + rowmax reduce (N..N+11) + thrmin (N+12)
// ---------------------------------------------------------------------------
__global__ __launch_bounds__(256) void k_router(
    const float* __restrict__ cnt, const float* __restrict__ rw,
    const float* rb, const float* rg, const float* rbeta,
    const float* rmean, const float* rvar,
    const float* __restrict__ const2,
    const float* __restrict__ rowmaxp, float* __restrict__ rowmax,
    const float* __restrict__ A, const float* __restrict__ Bc,
    float* __restrict__ thrmin,
    int* sel_e, float* sel_g, float* gsum, float* K,
    float* f_acc, float* p_acc) {
  __shared__ float sc[C_ + 256 + E_];
  __shared__ int s_i1, s_i2;
  __shared__ float s_g1, s_g2;
  int bid = blockIdx.x, tid = threadIdx.x;

  if (bid < N_) {
    int n = bid;
    float* part = sc + C_;
    float* lg = part + 256;
    for (int c = tid; c < C_; c += 256) sc[c] = cnt[(size_t)n * C_ + c];
    __syncthreads();
    {
      int e = tid >> 5, sub = tid & 31;
      float d = 0.f;
      for (int c = sub; c < C_; c += 32) d += rw[e * C_ + c] * sc[c];
      part[tid] = d;
    }
    __syncthreads();
    if (tid < E_) {
      float dot = 0.f;
      #pragma unroll
      for (int j = 0; j < 32; ++j) dot += part[tid * 32 + j];
      float inv = rg[tid] / sqrtf(rvar[tid] + 1e-5f);
      lg[tid] = (dot * (1.0f / HW_) + rb[tid]) * inv +
                (rbeta[tid] - rmean[tid] * inv);
    }
    __syncthreads();
    if (tid == 0) {
      float m = lg[0];
      for (int e = 1; e < E_; ++e) m = fmaxf(m, lg[e]);
      float pr[E_]; float s = 0.f;
      for (int e = 0; e < E_; ++e) { pr[e] = expf(lg[e] - m); s += pr[e]; }
      float invs = 1.0f / s;
      for (int e = 0; e < E_; ++e) pr[e] *= invs;
      int i1 = 0;
      for (int e = 1; e < E_; ++e) if (pr[e] > pr[i1]) i1 = e;
      int i2 = (i1 == 0) ? 1 : 0;
      for (int e = 0; e < E_; ++e) if (e != i1 && pr[e] > pr[i2]) i2 = e;
      float w = pr[i1] + pr[i2];
      float ga = pr[i1] / w, gb = pr[i2] / w;
      sel_e[2 * n] = i1; sel_e[2 * n + 1] = i2;
      sel_g[2 * n] = ga; sel_g[2 * n + 1] = gb;
      gsum[n] = ga + gb;
      s_i1 = i1; s_i2 = i2; s_g1 = ga; s_g2 = gb;
      atomicAdd(&f_acc[i1], 1.0f);
      atomicAdd(&f_acc[i2], 1.0f);
      for (int e = 0; e < E_; ++e) atomicAdd(&p_acc[e], pr[e]);
    }
    __syncthreads();
    int i1 = s_i1, i2 = s_i2; float ga = s_g1, gb = s_g2;
    for (int c = tid; c < C_; c += 256)
      K[(size_t)n * C_ + c] =
          ga * const2[i1 * C_ + c] + gb * const2[i2 * C_ + c];
  } else if (bid < N_ + 12) {
    // reduce rowmax partials: 3072 (e,c) entries
    int idx = (bid - N_) * 256 + tid;
    if (idx < E_ * C_) {
      float m = 0.f;
      #pragma unroll
      for (int t = 0; t < 24; ++t) m = fmaxf(m, rowmaxp[(size_t)idx * 24 + t]);
      rowmax[idx] = m;
    }
  } else {
    // thrmin[e] = min_o ( A!=0 ? -B/|A| : (B>=0 ? -inf : +inf) )
    float* red = sc;
    for (int e = 0; e < E_; ++e) {
      float m = INFINITY;
      for (int o = tid; o < HF_; o += 256) {
        float a = A[e * HF_ + o], b = Bc[e * HF_ + o];
        float thr = (a != 0.0f) ? (-b / fabsf(a))
                                : ((b >= 0.0f) ? -INFINITY : INFINITY);
        m = fminf(m, thr);
      }
      red[tid] = m;
      __syncthreads();
      for (int s = 128; s > 0; s >>= 1) {
        if (tid < s) red[tid] = fminf(red[tid], red[tid + s]);
        __syncthreads();
      }
      if (tid == 0) thrmin[e] = red[0];
      __syncthreads();
    }
  }
}

// ---------------------------------------------------------------------------
// K3: one block per pair (uniform expert). Stage levels[n] (75 KB) to LDS,
// build spike lists for 196 positions, certified bound-prune, compact
// survivors into a SINGLE queue (entry = tw | nnz<<20).
// ---------------------------------------------------------------------------
__global__ __launch_bounds__(256) void k_lists(
    const unsigned char* __restrict__ levels, const int* __restrict__ sel_e,
    const float* __restrict__ rowmax, const float* __restrict__ thrmin,
    unsigned short* __restrict__ list16,
    int* __restrict__ queue, int* __restrict__ qcount) {
  __shared__ unsigned char xs8[C_ * HW_];   // 75264 B
  __shared__ float rmx[C_];
  int bid = blockIdx.x, tid = threadIdx.x;
  int lane = tid & 63, wave = tid >> 6;
  int pair = bid, n = bid >> 1;
  int e = sel_e[pair];
  unsigned long long lmask = (1ull << lane) - 1ull;

  {
    const uint4* src = (const uint4*)(levels + (size_t)n * (C_ * HW_));
    uint4* dst = (uint4*)xs8;
    for (int i = tid; i < (C_ * HW_) / 16; i += 256) dst[i] = src[i];
  }
  for (int c = tid; c < C_; c += 256) rmx[c] = rowmax[e * C_ + c];
  __syncthreads();

  float thr = thrmin[e] - 1e-4f;
  for (int pos = wave; pos < HW_; pos += 4) {
    unsigned long long masks[6];
    int nnz = 0;
    float myb = 0.f;
    #pragma unroll
    for (int cb = 0; cb < 6; ++cb) {
      int c = cb * 64 + lane;
      bool sp = (int)xs8[c * HW_ + pos] > e;
      unsigned long long m = __ballot(sp);
      masks[cb] = m;
      if (sp) myb += rmx[c];
      nnz += __popcll(m);
    }
    // wave-sum the bound
    #pragma unroll
    for (int off = 1; off < 64; off <<= 1) myb += __shfl_xor(myb, off, 64);
    if (myb >= thr) {
      int tw = pair * HW_ + pos;
      size_t lbase = (size_t)tw * LCAP;
      int cum = 0;
      #pragma unroll
      for (int cb = 0; cb < 6; ++cb) {
        unsigned long long m = masks[cb];
        bool sp2 = (m >> lane) & 1ull;
        int p2 = cum + __popcll(m & lmask);
        if (sp2 && p2 < LCAP) list16[lbase + p2] = (unsigned short)(cb * 64 + lane);
        cum += __popcll(m);
      }
      if (lane == 0) {
        int nv = nnz < LCAP ? nnz : LCAP;
        int qi = atomicAdd(qcount, 1);
        queue[qi] = tw | (nv << 20);
      }
    }
  }
}

// ---------------------------------------------------------------------------
// K3b: streaming combine out = gsum[n]*x + K[n,c]  (thread per float4, coalesced)
// ---------------------------------------------------------------------------
__global__ __launch_bounds__(256) void k_combine(
    const float* __restrict__ x, const float* __restrict__ gsum,
    const float* __restrict__ K, float* __restrict__ out) {
  int idx = blockIdx.x * 256 + threadIdx.x;     // over N*C*49 float4s
  int nc = idx / 49;                            // (n,c) row
  float g = gsum[nc / C_];
  float kc = K[nc];
  float4 v = ((const float4*)x)[idx];
  v.x = g * v.x + kc;
  v.y = g * v.y + kc;
  v.z = g * v.z + kc;
  v.w = g * v.w + kc;
  ((float4*)out)[idx] = v;
}

// ---------------------------------------------------------------------------
// K4: gather — grid-stride over compacted queue; one wave per surviving task.
// 3 passes of 8 outputs/lane (spill-proof).  (round-1 proven structure)
// ---------------------------------------------------------------------------
__global__ __launch_bounds__(256, 4) void k_gather(
    const __hip_bfloat16* __restrict__ w1t,
    const float* __restrict__ A, const float* __restrict__ Bc,
    const int* __restrict__ sel_e,
    const int* __restrict__ queue, const int* __restrict__ qcount,
    const unsigned short* __restrict__ list16,
    int* __restrict__ rec, int* __restrict__ rec_count) {
  int nq = *qcount;
  int wid = blockIdx.x * 4 + (threadIdx.x >> 6);
  int lane = threadIdx.x & 63;
  int nwaves = gridDim.x * 4;

  for (int qi = wid; qi < nq; qi += nwaves) {
    int ent = queue[qi];
    int tw = ent & 0xFFFFF;
    int nnz = ent >> 20;
    int pair = tw / HW_, pos = tw - pair * HW_;
    int e = sel_e[pair];
    int lv = (int)list16[(size_t)tw * LCAP + lane];
    const uint4* wb = (const uint4*)(w1t + (size_t)e * C_ * HF_);  // 192 uint4/row

    #pragma unroll
    for (int pass = 0; pass < 3; ++pass) {
      const uint4* wbp = wb + pass * 64 + lane;
      float acc[8];
      #pragma unroll
      for (int q = 0; q < 8; ++q) acc[q] = 0.f;
      int j = 0;
      for (; j + 4 <= nnz; j += 4) {
        int c0 = __shfl(lv, j + 0);
        int c1 = __shfl(lv, j + 1);
        int c2 = __shfl(lv, j + 2);
        int c3 = __shfl(lv, j + 3);
        uint4 a = wbp[c0 * 192];
        uint4 b = wbp[c1 * 192];
        uint4 c = wbp[c2 * 192];
        uint4 d = wbp[c3 * 192];
        uint32_t ua[4] = {a.x, a.y, a.z, a.w};
        uint32_t ub[4] = {b.x, b.y, b.z, b.w};
        uint32_t uc[4] = {c.x, c.y, c.z, c.w};
        uint32_t ud[4] = {d.x, d.y, d.z, d.w};
        #pragma unroll
        for (int q = 0; q < 4; ++q) {
          acc[2 * q]     += __uint_as_float(ua[q] << 16) + __uint_as_float(ub[q] << 16) +
                            __uint_as_float(uc[q] << 16) + __uint_as_float(ud[q] << 16);
          acc[2 * q + 1] += __uint_as_float(ua[q] & 0xffff0000u) + __uint_as_float(ub[q] & 0xffff0000u) +
                            __uint_as_float(uc[q] & 0xffff0000u) + __uint_as_float(ud[q] & 0xffff0000u);
        }
      }
      for (; j < nnz; ++j) {
        int c0 = __shfl(lv, j);
        uint4 a = wbp[c0 * 192];
        uint32_t ua[4] = {a.x, a.y, a.z, a.w};
        #pragma unroll
        for (int q = 0; q < 4; ++q) {
          acc[2 * q]     += __uint_as_float(ua[q] << 16);
          acc[2 * q + 1] += __uint_as_float(ua[q] & 0xffff0000u);
        }
      }
      // threshold for my 8 outputs: o = (pass*64+lane)*8 + q
      int k2 = (pass * 64 + lane) * 2;
      float4 Av0 = ((const float4*)(A + e * HF_))[k2];
      float4 Av1 = ((const float4*)(A + e * HF_))[k2 + 1];
      float4 Bv0 = ((const float4*)(Bc + e * HF_))[k2];
      float4 Bv1 = ((const float4*)(Bc + e * HF_))[k2 + 1];
      float av[8] = {Av0.x, Av0.y, Av0.z, Av0.w, Av1.x, Av1.y, Av1.z, Av1.w};
      float bv[8] = {Bv0.x, Bv0.y, Bv0.z, Bv0.w, Bv1.x, Bv1.y, Bv1.z, Bv1.w};
      #pragma unroll
      for (int q = 0; q < 8; ++q) {
        if (av[q] * acc[q] + bv[q] >= 0.0f) {     // layer-2 spike (rare)
          int ridx = atomicAdd(rec_count, 1);
          if (ridx < REC_CAP) {
            rec[ridx * 3 + 0] = pair;
            rec[ridx * 3 + 1] = pos;
            rec[ridx * 3 + 2] = (pass * 64 + lane) * 8 + q;
          }
        }
      }
    }
  }
}

// ---------------------------------------------------------------------------
// K5: apply rare records; write aux
// ---------------------------------------------------------------------------
__global__ void k_apply(const int* __restrict__ rec, const int* __restrict__ rec_count,
                        const int* __restrict__ sel_e, const float* __restrict__ sel_g,
                        const float* __restrict__ inv2v, const float* __restrict__ w2,
                        const float* f_acc, const float* p_acc,
                        float* __restrict__ out, float* aux_out) {
  int nrec = *rec_count;
  if (nrec > REC_CAP) nrec = REC_CAP;
  for (int r = blockIdx.x; r < nrec; r += gridDim.x) {
    int pair = rec[r * 3], pos = rec[r * 3 + 1], o = rec[r * 3 + 2];
    int n = pair >> 1;
    int e = sel_e[pair];
    float g = sel_g[pair];
    for (int c = threadIdx.x; c < C_; c += blockDim.x) {
      float wv = w2[(size_t)(e * C_ + c) * HF_ + o];
      atomicAdd(&out[(size_t)(n * C_ + c) * HW_ + pos],
                g * inv2v[e * C_ + c] * wv);
    }
  }
  if (blockIdx.x == 0 && threadIdx.x == 0) {
    float s = 0.f;
    for (int e = 0; e < E_; ++e)
      s += (f_acc[e] * (1.0f / N_)) * (p_acc[e] * (1.0f / N_));
    *aux_out = 0.01f * E_ * s;
  }
}

// ---------------------------------------------------------------------------
// Workspace layout (bytes), total ~28.1 MB
// ---------------------------------------------------------------------------
extern "C" void kernel_launch(void* const* d_in, const int* in_sizes, int n_in,
                              void* d_out, int out_size, void* d_ws, size_t ws_size,
                              hipStream_t stream) {
  const float* x       = (const float*)d_in[0];
  const float* rw      = (const float*)d_in[1];
  const float* rb      = (const float*)d_in[2];
  const float* r_gamma = (const float*)d_in[3];
  const float* r_beta  = (const float*)d_in[4];
  const float* r_mean  = (const float*)d_in[5];
  const float* r_var   = (const float*)d_in[6];
  const float* w1      = (const float*)d_in[7];
  const float* b1      = (const float*)d_in[8];
  const float* g1      = (const float*)d_in[9];
  const float* be1     = (const float*)d_in[10];
  const float* m1      = (const float*)d_in[11];
  const float* v1      = (const float*)d_in[12];
  const float* w2      = (const float*)d_in[13];
  const float* b2      = (const float*)d_in[14];
  const float* g2      = (const float*)d_in[15];
  const float* be2     = (const float*)d_in[16];
  const float* m2      = (const float*)d_in[17];
  const float* v2      = (const float*)d_in[18];
  const float* taus    = (const float*)d_in[19];
  float* out = (float*)d_out;

  char* ws = (char*)d_ws;
  int*   header = (int*)ws;                 // [0]=rec_count, [1]=qcount
  float* f_acc  = (float*)ws + 8;
  float* p_acc  = (float*)ws + 16;
  int*   qcount = header + 1;
  float* cnt    = (float*)(ws + 256);       // 196608 B
  int*   sel_e  = (int*)(ws + 196864);
  float* sel_g  = (float*)(ws + 197888);
  float* gsum   = (float*)(ws + 198912);
  float* K      = (float*)(ws + 199424);    // 196608 B
  float* A      = (float*)(ws + 396032);
  float* Bc     = (float*)(ws + 445184);
  float* const2 = (float*)(ws + 494336);
  float* inv2v  = (float*)(ws + 506624);
  int*   rec    = (int*)(ws + 518912);      // 196608 B
  __hip_bfloat16* w1t = (__hip_bfloat16*)(ws + 715520);     // 9437184 B
  int*   queue  = (int*)(ws + 10152704);    // NGT*4 = 200704 B (region 1605632)
  unsigned short* list16 = (unsigned short*)(ws + 11758336); // 6422528 B
  unsigned char* levels  = (unsigned char*)(ws + 18180864);  // 9633792 B
  float* rowmaxp = (float*)(ws + 27814656); // 294912 B
  float* rowmax  = (float*)(ws + 28109568); // 12288 B
  float* thrmin  = (float*)(ws + 28121856); // 32 B

  k_lifprep<<<LIFB + TRB + PRB, 256, 0, stream>>>(
      x, cnt, levels, w1, w1t, b1, g1, be1, m1, v1, b2, g2, be2, m2, v2, taus,
      A, Bc, const2, inv2v, rowmaxp, header);
  k_router<<<N_ + 13, 256, 0, stream>>>(
      cnt, rw, rb, r_gamma, r_beta, r_mean, r_var, const2,
      rowmaxp, rowmax, A, Bc, thrmin,
      sel_e, sel_g, gsum, K, f_acc, p_acc);
  k_lists<<<NPAIR, 256, 0, stream>>>(
      levels, sel_e, rowmax, thrmin, list16, queue, qcount);
  k_combine<<<(N_ * C_ * 49) / 256, 256, 0, stream>>>(x, gsum, K, out);
  k_gather<<<2048, 256, 0, stream>>>(
      w1t, A, Bc, sel_e, queue, qcount, list16, rec, header);
  k_apply<<<64, 256, 0, stream>>>(
      rec, header, sel_e, sel_g, inv2v, w2, f_acc, p_acc,
      out, out + (out_size - 1));
}

// Round 4
// 221.071 us; speedup vs baseline: 1.2205x; 1.0810x over previous
//
#include <hip/hip_runtime.h>
#include <hip/hip_bf16.h>
#include <cstdint>
#include <math.h>

// Problem constants
#define T_  4
#define B_  32
#define C_  384
#define HF_ 1536
#define HW_ 196
#define E_  8
#define N_  128
#define NROW 1792          // (n,h) units
#define NGT  50176         // (pair,pos) tasks = 256*196
#define LCAP 64

#define LIFB (B_ * C_)        // 12288
#define TRB  (E_ * 12 * 24)   // 2304 transpose tiles
#define PRB  48

// ---------------------------------------------------------------------------
// K1: LIF spike counts + BN-const folding + w1 transpose->bf16 + rowmax partials
// ---------------------------------------------------------------------------
__global__ __launch_bounds__(256) void k_lifprep(
    const float* __restrict__ x, float* __restrict__ cnt,
    const float* __restrict__ w1, __hip_bfloat16* __restrict__ w1t,
    const float* b1, const float* g1, const float* be1,
    const float* m1, const float* v1,
    const float* b2, const float* g2, const float* be2,
    const float* m2, const float* v2,
    const float* taus,
    float* A, float* Bc, float* const2, float* inv2v,
    float* rowmaxp, int* header) {
  __shared__ float tile[64][33];
  __shared__ int c4[T_];
  int blk = blockIdx.x;
  int tid = threadIdx.x;

  if (blk < LIFB) {
    // ---- LIF ----
    if (tid < T_) c4[tid] = 0;
    __syncthreads();
    int bc = blk;
    bool act = tid < HW_;
    float v = 0.f;
    size_t base = (size_t)bc * HW_ + (act ? tid : 0);
    #pragma unroll
    for (int t = 0; t < T_; ++t) {
      float xv = act ? x[base + (size_t)t * B_ * C_ * HW_] : -1e30f;
      v = v + (xv - v) * 0.5f;                 // tau=2.0
      bool sp = (v - 1.0f >= 0.0f);
      if (sp) v = 0.f;
      unsigned long long m = __ballot(act && sp);
      if ((tid & 63) == 0) atomicAdd(&c4[t], __popcll(m));
    }
    __syncthreads();
    if (tid < T_) cnt[(size_t)tid * B_ * C_ + bc] = (float)c4[tid];
  } else if (blk < LIFB + TRB) {
    // ---- transpose w1 -> bf16 w1t + rowmax partials ----
    int rem = blk - LIFB;
    int e = rem / 288, r2 = rem % 288;
    int ct = r2 / 24, ot = r2 % 24;
    int c0 = ct * 32, o0 = ot * 64;
    int cl = tid & 31, olb = tid >> 5;
    #pragma unroll
    for (int it = 0; it < 8; ++it) {
      int ol = olb + it * 8;
      tile[ol][cl] = w1[(size_t)(e * HF_ + o0 + ol) * C_ + c0 + cl];
    }
    __syncthreads();
    int ol2 = tid & 63, clb = tid >> 6;
    #pragma unroll
    for (int it = 0; it < 8; ++it) {
      int cl2 = clb + it * 4;
      w1t[(size_t)(e * C_ + c0 + cl2) * HF_ + o0 + ol2] =
          __float2bfloat16(tile[ol2][cl2]);
    }
    // per-(c, ot) max |bf16(w1)| over this tile's 64 outputs (race-free partials)
    if (tid < 32) {
      float m = 0.f;
      for (int ol = 0; ol < 64; ++ol) {
        float bv = __bfloat162float(__float2bfloat16(tile[ol][tid]));
        m = fmaxf(m, fabsf(bv));
      }
      rowmaxp[(size_t)(e * C_ + c0 + tid) * 24 + ot] = m;
    }
  } else {
    // ---- prep ----
    int idx = (blk - LIFB - TRB) * 256 + tid;
    if (idx < 64) header[idx] = 0;
    if (idx < E_ * HF_) {
      int e = idx / HF_;
      float inv = g1[idx] / sqrtf(v1[idx] + 1e-5f);
      float sh  = be1[idx] - m1[idx] * inv;
      A[idx]  = inv;
      Bc[idx] = inv * b1[idx] + sh - taus[e];
    }
    if (idx < E_ * C_) {
      float inv = g2[idx] / sqrtf(v2[idx] + 1e-5f);
      const2[idx] = b2[idx] * inv + (be2[idx] - m2[idx] * inv);
      inv2v[idx]  = inv;
    }
  }
}

// ---------------------------------------------------------------------------
// K2: router (blocks 0..N-1) + rowmax reduce (N..N+11) + thrmin (N+12)
// ---------------------------------------------------------------------------
__global__ __launch_bounds__(256) void k_router(
    const float* __restrict__ cnt, const float* __restrict__ rw,
    const float* rb, const float* rg, const float* rbeta,
    const float* rmean, const float* rvar,
    const float* __restrict__ const2,
    const float* __restrict__ rowmaxp, float* __restrict__ rowmax,
    const float* __restrict__ A, const float* __restrict__ Bc,
    float* __restrict__ thrmin,
    int* sel_e, float* sel_g, float* gsum, float* K,
    float* f_acc, float* p_acc) {
  __shared__ float sc[C_ + 256 + E_];
  __shared__ int s_i1, s_i2;
  __shared__ float s_g1, s_g2;
  int bid = blockIdx.x, tid = threadIdx.x;

  if (bid < N_) {
    int n = bid;
    float* part = sc + C_;
    float* lg = part + 256;
    for (int c = tid; c < C_; c += 256) sc[c] = cnt[(size_t)n * C_ + c];
    __syncthreads();
    {
      int e = tid >> 5, sub = tid & 31;
      float d = 0.f;
      for (int c = sub; c < C_; c += 32) d += rw[e * C_ + c] * sc[c];
      part[tid] = d;
    }
    __syncthreads();
    if (tid < E_) {
      float dot = 0.f;
      #pragma unroll
      for (int j = 0; j < 32; ++j) dot += part[tid * 32 + j];
      float inv = rg[tid] / sqrtf(rvar[tid] + 1e-5f);
      lg[tid] = (dot * (1.0f / HW_) + rb[tid]) * inv +
                (rbeta[tid] - rmean[tid] * inv);
    }
    __syncthreads();
    if (tid == 0) {
      float m = lg[0];
      for (int e = 1; e < E_; ++e) m = fmaxf(m, lg[e]);
      float pr[E_]; float s = 0.f;
      for (int e = 0; e < E_; ++e) { pr[e] = expf(lg[e] - m); s += pr[e]; }
      float invs = 1.0f / s;
      for (int e = 0; e < E_; ++e) pr[e] *= invs;
      int i1 = 0;
      for (int e = 1; e < E_; ++e) if (pr[e] > pr[i1]) i1 = e;
      int i2 = (i1 == 0) ? 1 : 0;
      for (int e = 0; e < E_; ++e) if (e != i1 && pr[e] > pr[i2]) i2 = e;
      float w = pr[i1] + pr[i2];
      float ga = pr[i1] / w, gb = pr[i2] / w;
      sel_e[2 * n] = i1; sel_e[2 * n + 1] = i2;
      sel_g[2 * n] = ga; sel_g[2 * n + 1] = gb;
      gsum[n] = ga + gb;
      s_i1 = i1; s_i2 = i2; s_g1 = ga; s_g2 = gb;
      atomicAdd(&f_acc[i1], 1.0f);
      atomicAdd(&f_acc[i2], 1.0f);
      for (int e = 0; e < E_; ++e) atomicAdd(&p_acc[e], pr[e]);
    }
    __syncthreads();
    int i1 = s_i1, i2 = s_i2; float ga = s_g1, gb = s_g2;
    for (int c = tid; c < C_; c += 256)
      K[(size_t)n * C_ + c] =
          ga * const2[i1 * C_ + c] + gb * const2[i2 * C_ + c];
  } else if (bid < N_ + 12) {
    // reduce rowmax partials: 3072 (e,c) entries
    int idx = (bid - N_) * 256 + tid;
    if (idx < E_ * C_) {
      float m = 0.f;
      #pragma unroll
      for (int t = 0; t < 24; ++t) m = fmaxf(m, rowmaxp[(size_t)idx * 24 + t]);
      rowmax[idx] = m;
    }
  } else {
    // thrmin[e] = min_o ( A!=0 ? -B/|A| : (B>=0 ? -inf : +inf) )
    float* red = sc;
    for (int e = 0; e < E_; ++e) {
      float m = INFINITY;
      for (int o = tid; o < HF_; o += 256) {
        float a = A[e * HF_ + o], b = Bc[e * HF_ + o];
        float thr = (a != 0.0f) ? (-b / fabsf(a))
                                : ((b >= 0.0f) ? -INFINITY : INFINITY);
        m = fminf(m, thr);
      }
      red[tid] = m;
      __syncthreads();
      for (int s = 128; s > 0; s >>= 1) {
        if (tid < s) red[tid] = fminf(red[tid], red[tid + s]);
        __syncthreads();
      }
      if (tid == 0) thrmin[e] = red[0];
      __syncthreads();
    }
  }
}

// ---------------------------------------------------------------------------
// K3: per (n,h): stage x, build spike lists for 28 (expert,w) tasks.
// Masks held in registers; list16 written ONLY for surviving (unpruned) tasks,
// which are compacted into a global queue (entry = tw | nnz<<20).
// Block 0 also writes the aux scalar (f/p complete after k_router).
// ---------------------------------------------------------------------------
__global__ __launch_bounds__(256) void k_lists(
    const float* __restrict__ x, const int* __restrict__ sel_e,
    const float* __restrict__ taus, const float* __restrict__ rowmax,
    const float* __restrict__ thrmin,
    unsigned short* __restrict__ list16,
    int* __restrict__ queue, int* __restrict__ qcount,
    const float* __restrict__ f_acc, const float* __restrict__ p_acc,
    float* __restrict__ aux_out) {
  __shared__ float xs[14 * 385];
  int bid = blockIdx.x, tid = threadIdx.x;
  int lane = tid & 63, wave = tid >> 6;
  int n = bid / 14, h = bid - n * 14;
  unsigned long long lmask = (1ull << lane) - 1ull;

  if (bid == 0 && tid == 0) {
    float s = 0.f;
    for (int e = 0; e < E_; ++e)
      s += (f_acc[e] * (1.0f / N_)) * (p_acc[e] * (1.0f / N_));
    *aux_out = 0.01f * E_ * s;
  }

  for (int idx = tid; idx < C_ * 7; idx += 256) {
    int c = idx / 7, wp = idx - c * 7;
    float2 v = *(const float2*)(x + ((size_t)(n * C_ + c) * 14 + h) * 14 + 2 * wp);
    xs[(2 * wp) * 385 + c]     = v.x;
    xs[(2 * wp + 1) * 385 + c] = v.y;
  }
  __syncthreads();

  for (int t = wave; t < 28; t += 4) {
    int k = t / 14, w = t - k * 14;
    int pair = 2 * n + k;
    int e = sel_e[pair];
    float tau = taus[e];
    const float* rme = rowmax + e * C_;
    unsigned long long masks[6];
    int nnz = 0;
    float myb = 0.f;
    #pragma unroll
    for (int cb = 0; cb < 6; ++cb) {
      int c = cb * 64 + lane;
      bool sp = (xs[w * 385 + c] / tau - 1.0f >= 0.0f);
      unsigned long long m = __ballot(sp);
      masks[cb] = m;
      if (sp) myb += rme[c];
      nnz += __popcll(m);
    }
    // wave-sum the bound (uniform after butterfly)
    #pragma unroll
    for (int off = 1; off < 64; off <<= 1) myb += __shfl_xor(myb, off, 64);
    bool prune = (myb < thrmin[e] - 1e-4f);
    if (!prune) {
      int tw = pair * 196 + h * 14 + w;
      size_t lbase = (size_t)tw * LCAP;
      int cum = 0;
      #pragma unroll
      for (int cb = 0; cb < 6; ++cb) {
        unsigned long long m = masks[cb];
        bool sp = (m >> lane) & 1ull;
        int pos = cum + __popcll(m & lmask);
        if (sp && pos < LCAP) list16[lbase + pos] = (unsigned short)(cb * 64 + lane);
        cum += __popcll(m);
      }
      if (lane == 0) {
        int nv = nnz < LCAP ? nnz : LCAP;
        int qi = atomicAdd(qcount, 1);
        queue[qi] = tw | (nv << 20);
      }
    }
  }
}

// ---------------------------------------------------------------------------
// K3b: streaming combine out = gsum[n]*x + K[n,c]  (thread per float4, coalesced)
// ---------------------------------------------------------------------------
__global__ __launch_bounds__(256) void k_combine(
    const float* __restrict__ x, const float* __restrict__ gsum,
    const float* __restrict__ K, float* __restrict__ out) {
  int idx = blockIdx.x * 256 + threadIdx.x;     // over N*C*49 float4s
  int nc = idx / 49;                            // (n,c) row
  float g = gsum[nc / C_];
  float kc = K[nc];
  float4 v = ((const float4*)x)[idx];
  v.x = g * v.x + kc;
  v.y = g * v.y + kc;
  v.z = g * v.z + kc;
  v.w = g * v.w + kc;
  ((float4*)out)[idx] = v;
}

// ---------------------------------------------------------------------------
// K4: gather — grid-stride over compacted queue; one wave per surviving task.
// 3 passes of 8 outputs/lane. Rare layer-2 spikes are applied IN-PLACE by the
// whole wave (384 cooperative atomics) — no rec round-trip, no k_apply.
// ---------------------------------------------------------------------------
__global__ __launch_bounds__(256, 4) void k_gather(
    const __hip_bfloat16* __restrict__ w1t,
    const float* __restrict__ A, const float* __restrict__ Bc,
    const int* __restrict__ sel_e, const float* __restrict__ sel_g,
    const int* __restrict__ queue, const int* __restrict__ qcount,
    const unsigned short* __restrict__ list16,
    const float* __restrict__ inv2v, const float* __restrict__ w2,
    float* __restrict__ out) {
  int nq = *qcount;
  int wid = blockIdx.x * 4 + (threadIdx.x >> 6);
  int lane = threadIdx.x & 63;
  int nwaves = gridDim.x * 4;

  for (int qi = wid; qi < nq; qi += nwaves) {
    int ent = queue[qi];
    int tw = ent & 0xFFFFF;
    int nnz = ent >> 20;
    int pair = tw / HW_, pos = tw - pair * HW_;
    int n = pair >> 1;
    int e = sel_e[pair];
    int lv = (int)list16[(size_t)tw * LCAP + lane];
    const uint4* wb = (const uint4*)(w1t + (size_t)e * C_ * HF_);  // 192 uint4/row

    #pragma unroll
    for (int pass = 0; pass < 3; ++pass) {
      const uint4* wbp = wb + pass * 64 + lane;
      float acc[8];
      #pragma unroll
      for (int q = 0; q < 8; ++q) acc[q] = 0.f;
      int j = 0;
      for (; j + 4 <= nnz; j += 4) {
        int c0 = __shfl(lv, j + 0);
        int c1 = __shfl(lv, j + 1);
        int c2 = __shfl(lv, j + 2);
        int c3 = __shfl(lv, j + 3);
        uint4 a = wbp[c0 * 192];
        uint4 b = wbp[c1 * 192];
        uint4 c = wbp[c2 * 192];
        uint4 d = wbp[c3 * 192];
        uint32_t ua[4] = {a.x, a.y, a.z, a.w};
        uint32_t ub[4] = {b.x, b.y, b.z, b.w};
        uint32_t uc[4] = {c.x, c.y, c.z, c.w};
        uint32_t ud[4] = {d.x, d.y, d.z, d.w};
        #pragma unroll
        for (int q = 0; q < 4; ++q) {
          acc[2 * q]     += __uint_as_float(ua[q] << 16) + __uint_as_float(ub[q] << 16) +
                            __uint_as_float(uc[q] << 16) + __uint_as_float(ud[q] << 16);
          acc[2 * q + 1] += __uint_as_float(ua[q] & 0xffff0000u) + __uint_as_float(ub[q] & 0xffff0000u) +
                            __uint_as_float(uc[q] & 0xffff0000u) + __uint_as_float(ud[q] & 0xffff0000u);
        }
      }
      for (; j < nnz; ++j) {
        int c0 = __shfl(lv, j);
        uint4 a = wbp[c0 * 192];
        uint32_t ua[4] = {a.x, a.y, a.z, a.w};
        #pragma unroll
        for (int q = 0; q < 4; ++q) {
          acc[2 * q]     += __uint_as_float(ua[q] << 16);
          acc[2 * q + 1] += __uint_as_float(ua[q] & 0xffff0000u);
        }
      }
      // threshold for my 8 outputs: o = (pass*64+lane)*8 + q
      int k2 = (pass * 64 + lane) * 2;
      float4 Av0 = ((const float4*)(A + e * HF_))[k2];
      float4 Av1 = ((const float4*)(A + e * HF_))[k2 + 1];
      float4 Bv0 = ((const float4*)(Bc + e * HF_))[k2];
      float4 Bv1 = ((const float4*)(Bc + e * HF_))[k2 + 1];
      float av[8] = {Av0.x, Av0.y, Av0.z, Av0.w, Av1.x, Av1.y, Av1.z, Av1.w};
      float bv[8] = {Bv0.x, Bv0.y, Bv0.z, Bv0.w, Bv1.x, Bv1.y, Bv1.z, Bv1.w};
      #pragma unroll
      for (int q = 0; q < 8; ++q) {
        unsigned long long fm = __ballot(av[q] * acc[q] + bv[q] >= 0.0f);
        while (fm) {                           // rare layer-2 spikes
          int b = __ffsll((unsigned long long)fm) - 1;
          fm &= fm - 1;
          int o = (pass * 64 + b) * 8 + q;
          float gk = sel_g[pair];
          const float* w2r = w2 + (size_t)e * C_ * HF_ + o;
          const float* ivr = inv2v + e * C_;
          for (int c = lane; c < C_; c += 64) {
            atomicAdd(&out[((size_t)(n * C_ + c)) * HW_ + pos],
                      gk * ivr[c] * w2r[(size_t)c * HF_]);
          }
        }
      }
    }
  }
}

// ---------------------------------------------------------------------------
// Workspace layout (bytes), total ~17.1 MB
// ---------------------------------------------------------------------------
extern "C" void kernel_launch(void* const* d_in, const int* in_sizes, int n_in,
                              void* d_out, int out_size, void* d_ws, size_t ws_size,
                              hipStream_t stream) {
  const float* x       = (const float*)d_in[0];
  const float* rw      = (const float*)d_in[1];
  const float* rb      = (const float*)d_in[2];
  const float* r_gamma = (const float*)d_in[3];
  const float* r_beta  = (const float*)d_in[4];
  const float* r_mean  = (const float*)d_in[5];
  const float* r_var   = (const float*)d_in[6];
  const float* w1      = (const float*)d_in[7];
  const float* b1      = (const float*)d_in[8];
  const float* g1      = (const float*)d_in[9];
  const float* be1     = (const float*)d_in[10];
  const float* m1      = (const float*)d_in[11];
  const float* v1      = (const float*)d_in[12];
  const float* w2      = (const float*)d_in[13];
  const float* b2      = (const float*)d_in[14];
  const float* g2      = (const float*)d_in[15];
  const float* be2     = (const float*)d_in[16];
  const float* m2      = (const float*)d_in[17];
  const float* v2      = (const float*)d_in[18];
  const float* taus    = (const float*)d_in[19];
  float* out = (float*)d_out;

  char* ws = (char*)d_ws;
  int*   header = (int*)ws;           // [1]=queue count
  float* f_acc  = (float*)ws + 8;
  float* p_acc  = (float*)ws + 16;
  float* cnt    = (float*)(ws + 256);
  int*   sel_e  = (int*)(ws + 196864);
  float* sel_g  = (float*)(ws + 197888);
  float* gsum   = (float*)(ws + 198912);
  float* K      = (float*)(ws + 199424);
  float* A      = (float*)(ws + 396032);
  float* Bc     = (float*)(ws + 445184);
  float* const2 = (float*)(ws + 494336);
  float* inv2v  = (float*)(ws + 506624);
  __hip_bfloat16* w1t = (__hip_bfloat16*)(ws + 715520);
  int*   queue  = (int*)(ws + 10152704);
  unsigned short* list16 = (unsigned short*)(ws + 10353408);
  float* rowmaxp = (float*)(ws + 16775936);
  float* rowmax  = (float*)(ws + 17070848);
  float* thrmin  = (float*)(ws + 17083136);
  int* qcount = header + 1;

  k_lifprep<<<LIFB + TRB + PRB, 256, 0, stream>>>(
      x, cnt, w1, w1t, b1, g1, be1, m1, v1, b2, g2, be2, m2, v2, taus,
      A, Bc, const2, inv2v, rowmaxp, header);
  k_router<<<N_ + 13, 256, 0, stream>>>(
      cnt, rw, rb, r_gamma, r_beta, r_mean, r_var, const2,
      rowmaxp, rowmax, A, Bc, thrmin,
      sel_e, sel_g, gsum, K, f_acc, p_acc);
  k_lists<<<NROW, 256, 0, stream>>>(
      x, sel_e, taus, rowmax, thrmin, list16, queue, qcount,
      f_acc, p_acc, out + (out_size - 1));
  k_combine<<<(N_ * C_ * 49) / 256, 256, 0, stream>>>(x, gsum, K, out);
  k_gather<<<2048, 256, 0, stream>>>(
      w1t, A, Bc, sel_e, sel_g, queue, qcount, list16, inv2v, w2, out);
}

// Round 5
// 201.690 us; speedup vs baseline: 1.3377x; 1.0961x over previous
//
#include <hip/hip_runtime.h>
#include <hip/hip_bf16.h>
#include <cstdint>
#include <math.h>

// Problem constants
#define T_  4
#define B_  32
#define C_  384
#define HF_ 1536
#define HW_ 196
#define E_  8
#define N_  128
#define NROW 1792          // (n,h) units
#define NGT  50176         // (pair,pos) tasks = 256*196
#define LCAP 64

#define LIFW (B_ * C_ / 4)    // 3072 blocks, 4 waves each, wave per (b,c) row
#define TRB  (E_ * 12 * 24)   // 2304 transpose tiles
#define PRB  48
#define COMBB ((N_ * C_ * 49) / 256)   // 9408 combine blocks

// ---------------------------------------------------------------------------
// K1: LIF spike counts (wave-per-row, float4) + BN-const folding +
//     w1 transpose->bf16 + rowmax partials + exact per-expert thresholds te
// ---------------------------------------------------------------------------
__global__ __launch_bounds__(256) void k_lifprep(
    const float* __restrict__ x, float* __restrict__ cnt,
    const float* __restrict__ w1, __hip_bfloat16* __restrict__ w1t,
    const float* b1, const float* g1, const float* be1,
    const float* m1, const float* v1,
    const float* b2, const float* g2, const float* be2,
    const float* m2, const float* v2,
    const float* taus,
    float* A, float* Bc, float* const2, float* inv2v,
    float* rowmaxp, int* header, float* te_g) {
  __shared__ float tile[64][33];
  int blk = blockIdx.x;
  int tid = threadIdx.x;

  if (blk < LIFW) {
    // ---- LIF: one wave per (b,c) row; lane handles 4 positions via float4 ----
    int lane = tid & 63, wave = tid >> 6;
    int bc = blk * 4 + wave;
    bool act = lane < 49;                       // 49 float4 = 196 positions
    const float4* xr = (const float4*)x;
    size_t rb = (size_t)bc * 49 + (act ? lane : 0);
    const size_t ts4 = (size_t)B_ * C_ * 49;    // t-stride in float4s
    float4 v = {0.f, 0.f, 0.f, 0.f};
    unsigned int counts = 0;                    // 4 x 8-bit packed per-t counts
    #pragma unroll
    for (int t = 0; t < T_; ++t) {
      float4 xv;
      if (act) xv = xr[rb + (size_t)t * ts4];
      else { xv.x = xv.y = xv.z = xv.w = -1e30f; }
      v.x = v.x + (xv.x - v.x) * 0.5f;          // tau=2.0
      v.y = v.y + (xv.y - v.y) * 0.5f;
      v.z = v.z + (xv.z - v.z) * 0.5f;
      v.w = v.w + (xv.w - v.w) * 0.5f;
      int cl = 0;
      if (v.x - 1.0f >= 0.0f) { v.x = 0.f; ++cl; }
      if (v.y - 1.0f >= 0.0f) { v.y = 0.f; ++cl; }
      if (v.z - 1.0f >= 0.0f) { v.z = 0.f; ++cl; }
      if (v.w - 1.0f >= 0.0f) { v.w = 0.f; ++cl; }
      counts += (unsigned int)cl << (8 * t);
    }
    #pragma unroll
    for (int off = 1; off < 64; off <<= 1)
      counts += (unsigned int)__shfl_xor((int)counts, off, 64);
    if (lane == 0) {
      #pragma unroll
      for (int t = 0; t < T_; ++t)
        cnt[(size_t)t * B_ * C_ + bc] = (float)((counts >> (8 * t)) & 0xffu);
    }
  } else if (blk < LIFW + TRB) {
    // ---- transpose w1 -> bf16 w1t + rowmax partials ----
    int rem = blk - LIFW;
    int e = rem / 288, r2 = rem % 288;
    int ct = r2 / 24, ot = r2 % 24;
    int c0 = ct * 32, o0 = ot * 64;
    int cl = tid & 31, olb = tid >> 5;
    #pragma unroll
    for (int it = 0; it < 8; ++it) {
      int ol = olb + it * 8;
      tile[ol][cl] = w1[(size_t)(e * HF_ + o0 + ol) * C_ + c0 + cl];
    }
    __syncthreads();
    int ol2 = tid & 63, clb = tid >> 6;
    #pragma unroll
    for (int it = 0; it < 8; ++it) {
      int cl2 = clb + it * 4;
      w1t[(size_t)(e * C_ + c0 + cl2) * HF_ + o0 + ol2] =
          __float2bfloat16(tile[ol2][cl2]);
    }
    // per-(c, ot) max |bf16(w1)| over this tile's 64 outputs (race-free partials)
    if (tid < 32) {
      float m = 0.f;
      for (int ol = 0; ol < 64; ++ol) {
        float bv = __bfloat162float(__float2bfloat16(tile[ol][tid]));
        m = fmaxf(m, fabsf(bv));
      }
      rowmaxp[(size_t)(e * C_ + c0 + tid) * 24 + ot] = m;
    }
  } else {
    // ---- prep ----
    int idx = (blk - LIFW - TRB) * 256 + tid;
    if (idx < 64) header[idx] = 0;
    if (idx < E_) {
      // te[e] = min{y : y/tau_e - 1 >= 0}; exact via 4-ulp monotone walk
      float t = taus[idx];
      float y = t;                      // y/t == 1.0 exactly -> satisfies
      #pragma unroll
      for (int it = 0; it < 4; ++it) {
        float cnd = __uint_as_float(__float_as_uint(y) - 1u);
        if (cnd / t - 1.0f >= 0.0f) y = cnd; else break;
      }
      te_g[idx] = y;
    }
    if (idx < E_ * HF_) {
      int e = idx / HF_;
      float inv = g1[idx] / sqrtf(v1[idx] + 1e-5f);
      float sh  = be1[idx] - m1[idx] * inv;
      A[idx]  = inv;
      Bc[idx] = inv * b1[idx] + sh - taus[e];
    }
    if (idx < E_ * C_) {
      float inv = g2[idx] / sqrtf(v2[idx] + 1e-5f);
      const2[idx] = b2[idx] * inv + (be2[idx] - m2[idx] * inv);
      inv2v[idx]  = inv;
    }
  }
}

// ---------------------------------------------------------------------------
// K2: router (blocks 0..N-1) + rowmax reduce (N..N+11) + thrmin (N+12)
// ---------------------------------------------------------------------------
__global__ __launch_bounds__(256) void k_router(
    const float* __restrict__ cnt, const float* __restrict__ rw,
    const float* rb, const float* rg, const float* rbeta,
    const float* rmean, const float* rvar,
    const float* __restrict__ const2,
    const float* __restrict__ rowmaxp, float* __restrict__ rowmax,
    const float* __restrict__ A, const float* __restrict__ Bc,
    float* __restrict__ thrmin,
    int* sel_e, float* sel_g, float* gsum, float* K,
    float* f_acc, float* p_acc) {
  __shared__ float sc[C_ + 256 + E_];
  __shared__ int s_i1, s_i2;
  __shared__ float s_g1, s_g2;
  int bid = blockIdx.x, tid = threadIdx.x;

  if (bid < N_) {
    int n = bid;
    float* part = sc + C_;
    float* lg = part + 256;
    for (int c = tid; c < C_; c += 256) sc[c] = cnt[(size_t)n * C_ + c];
    __syncthreads();
    {
      int e = tid >> 5, sub = tid & 31;
      float d = 0.f;
      for (int c = sub; c < C_; c += 32) d += rw[e * C_ + c] * sc[c];
      part[tid] = d;
    }
    __syncthreads();
    if (tid < E_) {
      float dot = 0.f;
      #pragma unroll
      for (int j = 0; j < 32; ++j) dot += part[tid * 32 + j];
      float inv = rg[tid] / sqrtf(rvar[tid] + 1e-5f);
      lg[tid] = (dot * (1.0f / HW_) + rb[tid]) * inv +
                (rbeta[tid] - rmean[tid] * inv);
    }
    __syncthreads();
    if (tid == 0) {
      float m = lg[0];
      for (int e = 1; e < E_; ++e) m = fmaxf(m, lg[e]);
      float pr[E_]; float s = 0.f;
      for (int e = 0; e < E_; ++e) { pr[e] = expf(lg[e] - m); s += pr[e]; }
      float invs = 1.0f / s;
      for (int e = 0; e < E_; ++e) pr[e] *= invs;
      int i1 = 0;
      for (int e = 1; e < E_; ++e) if (pr[e] > pr[i1]) i1 = e;
      int i2 = (i1 == 0) ? 1 : 0;
      for (int e = 0; e < E_; ++e) if (e != i1 && pr[e] > pr[i2]) i2 = e;
      float w = pr[i1] + pr[i2];
      float ga = pr[i1] / w, gb = pr[i2] / w;
      sel_e[2 * n] = i1; sel_e[2 * n + 1] = i2;
      sel_g[2 * n] = ga; sel_g[2 * n + 1] = gb;
      gsum[n] = ga + gb;
      s_i1 = i1; s_i2 = i2; s_g1 = ga; s_g2 = gb;
      atomicAdd(&f_acc[i1], 1.0f);
      atomicAdd(&f_acc[i2], 1.0f);
      for (int e = 0; e < E_; ++e) atomicAdd(&p_acc[e], pr[e]);
    }
    __syncthreads();
    int i1 = s_i1, i2 = s_i2; float ga = s_g1, gb = s_g2;
    for (int c = tid; c < C_; c += 256)
      K[(size_t)n * C_ + c] =
          ga * const2[i1 * C_ + c] + gb * const2[i2 * C_ + c];
  } else if (bid < N_ + 12) {
    // reduce rowmax partials: 3072 (e,c) entries
    int idx = (bid - N_) * 256 + tid;
    if (idx < E_ * C_) {
      float m = 0.f;
      #pragma unroll
      for (int t = 0; t < 24; ++t) m = fmaxf(m, rowmaxp[(size_t)idx * 24 + t]);
      rowmax[idx] = m;
    }
  } else {
    // thrmin[e] = min_o ( A!=0 ? -B/|A| : (B>=0 ? -inf : +inf) )
    float* red = sc;
    for (int e = 0; e < E_; ++e) {
      float m = INFINITY;
      for (int o = tid; o < HF_; o += 256) {
        float a = A[e * HF_ + o], b = Bc[e * HF_ + o];
        float thr = (a != 0.0f) ? (-b / fabsf(a))
                                : ((b >= 0.0f) ? -INFINITY : INFINITY);
        m = fminf(m, thr);
      }
      red[tid] = m;
      __syncthreads();
      for (int s = 128; s > 0; s >>= 1) {
        if (tid < s) red[tid] = fminf(red[tid], red[tid + s]);
        __syncthreads();
      }
      if (tid == 0) thrmin[e] = red[0];
      __syncthreads();
    }
  }
}

// ---------------------------------------------------------------------------
// K3: blocks [0,NROW): per (n,h) stage x, build spike lists for 28 (expert,w)
//     tasks via te-compare (no divides); certified bound-prune; survivors into
//     a global queue. Block 0 writes aux.
//     blocks [NROW, NROW+COMBB): streaming combine out = gsum*x + K.
// ---------------------------------------------------------------------------
__global__ __launch_bounds__(256) void k_lists(
    const float* __restrict__ x, const int* __restrict__ sel_e,
    const float* __restrict__ te_g, const float* __restrict__ rowmax,
    const float* __restrict__ thrmin,
    unsigned short* __restrict__ list16,
    int* __restrict__ queue, int* __restrict__ qcount,
    const float* __restrict__ f_acc, const float* __restrict__ p_acc,
    float* __restrict__ aux_out,
    const float* __restrict__ gsum, const float* __restrict__ K,
    float* __restrict__ out) {
  __shared__ float xs[14 * 385];
  int bid = blockIdx.x, tid = threadIdx.x;

  if (bid >= NROW) {
    // ---- combine blocks: thread per float4, coalesced ----
    int idx = (bid - NROW) * 256 + tid;         // over N*C*49 float4s
    int nc = idx / 49;                          // (n,c) row
    float g = gsum[nc / C_];
    float kc = K[nc];
    float4 v = ((const float4*)x)[idx];
    v.x = g * v.x + kc;
    v.y = g * v.y + kc;
    v.z = g * v.z + kc;
    v.w = g * v.w + kc;
    ((float4*)out)[idx] = v;
    return;
  }

  int lane = tid & 63, wave = tid >> 6;
  int n = bid / 14, h = bid - n * 14;
  unsigned long long lmask = (1ull << lane) - 1ull;

  if (bid == 0 && tid == 0) {
    float s = 0.f;
    for (int e = 0; e < E_; ++e)
      s += (f_acc[e] * (1.0f / N_)) * (p_acc[e] * (1.0f / N_));
    *aux_out = 0.01f * E_ * s;
  }

  for (int idx = tid; idx < C_ * 7; idx += 256) {
    int c = idx / 7, wp = idx - c * 7;
    float2 v = *(const float2*)(x + ((size_t)(n * C_ + c) * 14 + h) * 14 + 2 * wp);
    xs[(2 * wp) * 385 + c]     = v.x;
    xs[(2 * wp + 1) * 385 + c] = v.y;
  }
  __syncthreads();

  for (int t = wave; t < 28; t += 4) {
    int k = t / 14, w = t - k * 14;
    int pair = 2 * n + k;
    int e = sel_e[pair];
    float tee = te_g[e];
    const float* rme = rowmax + e * C_;
    unsigned long long masks[6];
    int nnz = 0;
    float myb = 0.f;
    #pragma unroll
    for (int cb = 0; cb < 6; ++cb) {
      int c = cb * 64 + lane;
      bool sp = (xs[w * 385 + c] >= tee);       // == x/tau - 1 >= 0, exact
      unsigned long long m = __ballot(sp);
      masks[cb] = m;
      if (sp) myb += rme[c];
      nnz += __popcll(m);
    }
    // wave-sum the bound (uniform after butterfly)
    #pragma unroll
    for (int off = 1; off < 64; off <<= 1) myb += __shfl_xor(myb, off, 64);
    bool prune = (myb < thrmin[e] - 1e-4f);
    if (!prune) {
      int tw = pair * 196 + h * 14 + w;
      size_t lbase = (size_t)tw * LCAP;
      int cum = 0;
      #pragma unroll
      for (int cb = 0; cb < 6; ++cb) {
        unsigned long long m = masks[cb];
        bool sp = (m >> lane) & 1ull;
        int pos = cum + __popcll(m & lmask);
        if (sp && pos < LCAP) list16[lbase + pos] = (unsigned short)(cb * 64 + lane);
        cum += __popcll(m);
      }
      if (lane == 0) {
        int nv = nnz < LCAP ? nnz : LCAP;
        int qi = atomicAdd(qcount, 1);
        queue[qi] = tw | (nv << 20);
      }
    }
  }
}

// ---------------------------------------------------------------------------
// K4: gather — grid-stride over compacted queue; one wave per surviving task.
// 3 passes of 8 outputs/lane. Rare layer-2 spikes applied in-place by the wave.
// ---------------------------------------------------------------------------
__global__ __launch_bounds__(256, 4) void k_gather(
    const __hip_bfloat16* __restrict__ w1t,
    const float* __restrict__ A, const float* __restrict__ Bc,
    const int* __restrict__ sel_e, const float* __restrict__ sel_g,
    const int* __restrict__ queue, const int* __restrict__ qcount,
    const unsigned short* __restrict__ list16,
    const float* __restrict__ inv2v, const float* __restrict__ w2,
    float* __restrict__ out) {
  int nq = *qcount;
  int wid = blockIdx.x * 4 + (threadIdx.x >> 6);
  int lane = threadIdx.x & 63;
  int nwaves = gridDim.x * 4;

  for (int qi = wid; qi < nq; qi += nwaves) {
    int ent = queue[qi];
    int tw = ent & 0xFFFFF;
    int nnz = ent >> 20;
    int pair = tw / HW_, pos = tw - pair * HW_;
    int n = pair >> 1;
    int e = sel_e[pair];
    int lv = (int)list16[(size_t)tw * LCAP + lane];
    const uint4* wb = (const uint4*)(w1t + (size_t)e * C_ * HF_);  // 192 uint4/row

    #pragma unroll
    for (int pass = 0; pass < 3; ++pass) {
      const uint4* wbp = wb + pass * 64 + lane;
      float acc[8];
      #pragma unroll
      for (int q = 0; q < 8; ++q) acc[q] = 0.f;
      int j = 0;
      for (; j + 4 <= nnz; j += 4) {
        int c0 = __shfl(lv, j + 0);
        int c1 = __shfl(lv, j + 1);
        int c2 = __shfl(lv, j + 2);
        int c3 = __shfl(lv, j + 3);
        uint4 a = wbp[c0 * 192];
        uint4 b = wbp[c1 * 192];
        uint4 c = wbp[c2 * 192];
        uint4 d = wbp[c3 * 192];
        uint32_t ua[4] = {a.x, a.y, a.z, a.w};
        uint32_t ub[4] = {b.x, b.y, b.z, b.w};
        uint32_t uc[4] = {c.x, c.y, c.z, c.w};
        uint32_t ud[4] = {d.x, d.y, d.z, d.w};
        #pragma unroll
        for (int q = 0; q < 4; ++q) {
          acc[2 * q]     += __uint_as_float(ua[q] << 16) + __uint_as_float(ub[q] << 16) +
                            __uint_as_float(uc[q] << 16) + __uint_as_float(ud[q] << 16);
          acc[2 * q + 1] += __uint_as_float(ua[q] & 0xffff0000u) + __uint_as_float(ub[q] & 0xffff0000u) +
                            __uint_as_float(uc[q] & 0xffff0000u) + __uint_as_float(ud[q] & 0xffff0000u);
        }
      }
      for (; j < nnz; ++j) {
        int c0 = __shfl(lv, j);
        uint4 a = wbp[c0 * 192];
        uint32_t ua[4] = {a.x, a.y, a.z, a.w};
        #pragma unroll
        for (int q = 0; q < 4; ++q) {
          acc[2 * q]     += __uint_as_float(ua[q] << 16);
          acc[2 * q + 1] += __uint_as_float(ua[q] & 0xffff0000u);
        }
      }
      // threshold for my 8 outputs: o = (pass*64+lane)*8 + q
      int k2 = (pass * 64 + lane) * 2;
      float4 Av0 = ((const float4*)(A + e * HF_))[k2];
      float4 Av1 = ((const float4*)(A + e * HF_))[k2 + 1];
      float4 Bv0 = ((const float4*)(Bc + e * HF_))[k2];
      float4 Bv1 = ((const float4*)(Bc + e * HF_))[k2 + 1];
      float av[8] = {Av0.x, Av0.y, Av0.z, Av0.w, Av1.x, Av1.y, Av1.z, Av1.w};
      float bv[8] = {Bv0.x, Bv0.y, Bv0.z, Bv0.w, Bv1.x, Bv1.y, Bv1.z, Bv1.w};
      #pragma unroll
      for (int q = 0; q < 8; ++q) {
        unsigned long long fm = __ballot(av[q] * acc[q] + bv[q] >= 0.0f);
        while (fm) {                           // rare layer-2 spikes
          int b = __ffsll((unsigned long long)fm) - 1;
          fm &= fm - 1;
          int o = (pass * 64 + b) * 8 + q;
          float gk = sel_g[pair];
          const float* w2r = w2 + (size_t)e * C_ * HF_ + o;
          const float* ivr = inv2v + e * C_;
          for (int c = lane; c < C_; c += 64) {
            atomicAdd(&out[((size_t)(n * C_ + c)) * HW_ + pos],
                      gk * ivr[c] * w2r[(size_t)c * HF_]);
          }
        }
      }
    }
  }
}

// ---------------------------------------------------------------------------
// Workspace layout (bytes), total ~17.1 MB
// ---------------------------------------------------------------------------
extern "C" void kernel_launch(void* const* d_in, const int* in_sizes, int n_in,
                              void* d_out, int out_size, void* d_ws, size_t ws_size,
                              hipStream_t stream) {
  const float* x       = (const float*)d_in[0];
  const float* rw      = (const float*)d_in[1];
  const float* rb      = (const float*)d_in[2];
  const float* r_gamma = (const float*)d_in[3];
  const float* r_beta  = (const float*)d_in[4];
  const float* r_mean  = (const float*)d_in[5];
  const float* r_var   = (const float*)d_in[6];
  const float* w1      = (const float*)d_in[7];
  const float* b1      = (const float*)d_in[8];
  const float* g1      = (const float*)d_in[9];
  const float* be1     = (const float*)d_in[10];
  const float* m1      = (const float*)d_in[11];
  const float* v1      = (const float*)d_in[12];
  const float* w2      = (const float*)d_in[13];
  const float* b2      = (const float*)d_in[14];
  const float* g2      = (const float*)d_in[15];
  const float* be2     = (const float*)d_in[16];
  const float* m2      = (const float*)d_in[17];
  const float* v2      = (const float*)d_in[18];
  const float* taus    = (const float*)d_in[19];
  float* out = (float*)d_out;

  char* ws = (char*)d_ws;
  int*   header = (int*)ws;           // [1]=queue count
  float* f_acc  = (float*)ws + 8;
  float* p_acc  = (float*)ws + 16;
  float* cnt    = (float*)(ws + 256);
  int*   sel_e  = (int*)(ws + 196864);
  float* sel_g  = (float*)(ws + 197888);
  float* gsum   = (float*)(ws + 198912);
  float* K      = (float*)(ws + 199424);
  float* A      = (float*)(ws + 396032);
  float* Bc     = (float*)(ws + 445184);
  float* const2 = (float*)(ws + 494336);
  float* inv2v  = (float*)(ws + 506624);
  __hip_bfloat16* w1t = (__hip_bfloat16*)(ws + 715520);
  int*   queue  = (int*)(ws + 10152704);
  unsigned short* list16 = (unsigned short*)(ws + 10353408);
  float* rowmaxp = (float*)(ws + 16775936);
  float* rowmax  = (float*)(ws + 17070848);
  float* thrmin  = (float*)(ws + 17083136);
  float* te_g    = (float*)(ws + 17083200);
  int* qcount = header + 1;

  k_lifprep<<<LIFW + TRB + PRB, 256, 0, stream>>>(
      x, cnt, w1, w1t, b1, g1, be1, m1, v1, b2, g2, be2, m2, v2, taus,
      A, Bc, const2, inv2v, rowmaxp, header, te_g);
  k_router<<<N_ + 13, 256, 0, stream>>>(
      cnt, rw, rb, r_gamma, r_beta, r_mean, r_var, const2,
      rowmaxp, rowmax, A, Bc, thrmin,
      sel_e, sel_g, gsum, K, f_acc, p_acc);
  k_lists<<<NROW + COMBB, 256, 0, stream>>>(
      x, sel_e, te_g, rowmax, thrmin, list16, queue, qcount,
      f_acc, p_acc, out + (out_size - 1), gsum, K, out);
  k_gather<<<2048, 256, 0, stream>>>(
      w1t, A, Bc, sel_e, sel_g, queue, qcount, list16, inv2v, w2, out);
}

// Round 6
// 201.376 us; speedup vs baseline: 1.3398x; 1.0016x over previous
//
#include <hip/hip_runtime.h>
#include <hip/hip_bf16.h>
#include <cstdint>
#include <math.h>

// Problem constants
#define T_  4
#define B_  32
#define C_  384
#define HF_ 1536
#define HW_ 196
#define E_  8
#define N_  128
#define NROW 1792          // (n,h) units
#define NGT  50176         // (pair,pos) tasks = 256*196
#define LCAP 64

#define LIFW (B_ * C_ / 4)    // 3072 blocks, 4 waves each, wave per (b,c) row
#define TRB  (E_ * 12 * 24)   // 2304 transpose tiles
#define PRB  48
#define COMBB ((N_ * C_ * 49) / 256)   // 9408 combine blocks

// ---------------------------------------------------------------------------
// K1: LIF spike counts (wave-per-row, float4) + per-element expert "level"
//     (u8, packed uint stores) + BN-const folding + w1 transpose->bf16 +
//     rowmax partials.
// level(x) = #{e : x >= te[e]}, te[e] = min{y : y/tau_e - 1 >= 0} (exact,
// monotone divide walk; taus ascending => spike for expert e <=> level > e).
// ---------------------------------------------------------------------------
__global__ __launch_bounds__(256) void k_lifprep(
    const float* __restrict__ x, float* __restrict__ cnt,
    unsigned int* __restrict__ levels4,
    const float* __restrict__ w1, __hip_bfloat16* __restrict__ w1t,
    const float* b1, const float* g1, const float* be1,
    const float* m1, const float* v1,
    const float* b2, const float* g2, const float* be2,
    const float* m2, const float* v2,
    const float* taus,
    float* A, float* Bc, float* const2, float* inv2v,
    float* rowmaxp, int* header) {
  __shared__ float tile[64][33];
  int blk = blockIdx.x;
  int tid = threadIdx.x;

  if (blk < LIFW) {
    // ---- LIF + levels: one wave per (b,c) row; lane = 4 positions (float4) ----
    int lane = tid & 63, wave = tid >> 6;
    int bc = blk * 4 + wave;
    bool act = lane < 49;                       // 49 float4 = 196 positions
    // exact per-expert thresholds (uniform across lanes, cheap)
    float te[E_];
    #pragma unroll
    for (int e2 = 0; e2 < E_; ++e2) {
      float t = taus[e2];
      float y = t;                              // y/t == 1.0 -> satisfies
      #pragma unroll
      for (int it = 0; it < 4; ++it) {
        float cnd = __uint_as_float(__float_as_uint(y) - 1u);
        if (cnd / t - 1.0f >= 0.0f) y = cnd; else break;
      }
      te[e2] = y;
    }
    const float4* xr = (const float4*)x;
    size_t rb = (size_t)bc * 49 + (act ? lane : 0);
    const size_t ts4 = (size_t)B_ * C_ * 49;    // t-stride in float4s
    float4 v = {0.f, 0.f, 0.f, 0.f};
    unsigned int counts = 0;                    // 4 x 8-bit packed per-t counts
    unsigned int pk[T_];
    #pragma unroll
    for (int t = 0; t < T_; ++t) {
      float4 xv;
      if (act) xv = xr[rb + (size_t)t * ts4];
      else { xv.x = xv.y = xv.z = xv.w = -1e30f; }
      // levels from RAW x (independent of LIF chain)
      int l0 = 0, l1 = 0, l2 = 0, l3 = 0;
      #pragma unroll
      for (int e2 = 0; e2 < E_; ++e2) {
        l0 += (xv.x >= te[e2]) ? 1 : 0;
        l1 += (xv.y >= te[e2]) ? 1 : 0;
        l2 += (xv.z >= te[e2]) ? 1 : 0;
        l3 += (xv.w >= te[e2]) ? 1 : 0;
      }
      pk[t] = (unsigned int)l0 | ((unsigned int)l1 << 8) |
              ((unsigned int)l2 << 16) | ((unsigned int)l3 << 24);
      // LIF chain
      v.x = v.x + (xv.x - v.x) * 0.5f;          // tau=2.0
      v.y = v.y + (xv.y - v.y) * 0.5f;
      v.z = v.z + (xv.z - v.z) * 0.5f;
      v.w = v.w + (xv.w - v.w) * 0.5f;
      int cl = 0;
      if (v.x - 1.0f >= 0.0f) { v.x = 0.f; ++cl; }
      if (v.y - 1.0f >= 0.0f) { v.y = 0.f; ++cl; }
      if (v.z - 1.0f >= 0.0f) { v.z = 0.f; ++cl; }
      if (v.w - 1.0f >= 0.0f) { v.w = 0.f; ++cl; }
      counts += (unsigned int)cl << (8 * t);
    }
    if (act) {
      #pragma unroll
      for (int t = 0; t < T_; ++t)
        levels4[rb + (size_t)t * ts4] = pk[t];  // coalesced uint stores
    }
    #pragma unroll
    for (int off = 1; off < 64; off <<= 1)
      counts += (unsigned int)__shfl_xor((int)counts, off, 64);
    if (lane == 0) {
      #pragma unroll
      for (int t = 0; t < T_; ++t)
        cnt[(size_t)t * B_ * C_ + bc] = (float)((counts >> (8 * t)) & 0xffu);
    }
  } else if (blk < LIFW + TRB) {
    // ---- transpose w1 -> bf16 w1t + rowmax partials ----
    int rem = blk - LIFW;
    int e = rem / 288, r2 = rem % 288;
    int ct = r2 / 24, ot = r2 % 24;
    int c0 = ct * 32, o0 = ot * 64;
    int cl = tid & 31, olb = tid >> 5;
    #pragma unroll
    for (int it = 0; it < 8; ++it) {
      int ol = olb + it * 8;
      tile[ol][cl] = w1[(size_t)(e * HF_ + o0 + ol) * C_ + c0 + cl];
    }
    __syncthreads();
    int ol2 = tid & 63, clb = tid >> 6;
    #pragma unroll
    for (int it = 0; it < 8; ++it) {
      int cl2 = clb + it * 4;
      w1t[(size_t)(e * C_ + c0 + cl2) * HF_ + o0 + ol2] =
          __float2bfloat16(tile[ol2][cl2]);
    }
    // per-(c, ot) max |bf16(w1)| over this tile's 64 outputs (race-free partials)
    if (tid < 32) {
      float m = 0.f;
      for (int ol = 0; ol < 64; ++ol) {
        float bv = __bfloat162float(__float2bfloat16(tile[ol][tid]));
        m = fmaxf(m, fabsf(bv));
      }
      rowmaxp[(size_t)(e * C_ + c0 + tid) * 24 + ot] = m;
    }
  } else {
    // ---- prep ----
    int idx = (blk - LIFW - TRB) * 256 + tid;
    if (idx < 64) header[idx] = 0;
    if (idx < E_ * HF_) {
      int e = idx / HF_;
      float inv = g1[idx] / sqrtf(v1[idx] + 1e-5f);
      float sh  = be1[idx] - m1[idx] * inv;
      A[idx]  = inv;
      Bc[idx] = inv * b1[idx] + sh - taus[e];
    }
    if (idx < E_ * C_) {
      float inv = g2[idx] / sqrtf(v2[idx] + 1e-5f);
      const2[idx] = b2[idx] * inv + (be2[idx] - m2[idx] * inv);
      inv2v[idx]  = inv;
    }
  }
}

// ---------------------------------------------------------------------------
// K2: router (blocks 0..N-1) + rowmax reduce (N..N+11) + thrmin (N+12)
// ---------------------------------------------------------------------------
__global__ __launch_bounds__(256) void k_router(
    const float* __restrict__ cnt, const float* __restrict__ rw,
    const float* rb, const float* rg, const float* rbeta,
    const float* rmean, const float* rvar,
    const float* __restrict__ const2,
    const float* __restrict__ rowmaxp, float* __restrict__ rowmax,
    const float* __restrict__ A, const float* __restrict__ Bc,
    float* __restrict__ thrmin,
    int* sel_e, float* sel_g, float* gsum, float* K,
    float* f_acc, float* p_acc) {
  __shared__ float sc[C_ + 256 + E_];
  __shared__ int s_i1, s_i2;
  __shared__ float s_g1, s_g2;
  int bid = blockIdx.x, tid = threadIdx.x;

  if (bid < N_) {
    int n = bid;
    float* part = sc + C_;
    float* lg = part + 256;
    for (int c = tid; c < C_; c += 256) sc[c] = cnt[(size_t)n * C_ + c];
    __syncthreads();
    {
      int e = tid >> 5, sub = tid & 31;
      float d = 0.f;
      for (int c = sub; c < C_; c += 32) d += rw[e * C_ + c] * sc[c];
      part[tid] = d;
    }
    __syncthreads();
    if (tid < E_) {
      float dot = 0.f;
      #pragma unroll
      for (int j = 0; j < 32; ++j) dot += part[tid * 32 + j];
      float inv = rg[tid] / sqrtf(rvar[tid] + 1e-5f);
      lg[tid] = (dot * (1.0f / HW_) + rb[tid]) * inv +
                (rbeta[tid] - rmean[tid] * inv);
    }
    __syncthreads();
    if (tid == 0) {
      float m = lg[0];
      for (int e = 1; e < E_; ++e) m = fmaxf(m, lg[e]);
      float pr[E_]; float s = 0.f;
      for (int e = 0; e < E_; ++e) { pr[e] = expf(lg[e] - m); s += pr[e]; }
      float invs = 1.0f / s;
      for (int e = 0; e < E_; ++e) pr[e] *= invs;
      int i1 = 0;
      for (int e = 1; e < E_; ++e) if (pr[e] > pr[i1]) i1 = e;
      int i2 = (i1 == 0) ? 1 : 0;
      for (int e = 0; e < E_; ++e) if (e != i1 && pr[e] > pr[i2]) i2 = e;
      float w = pr[i1] + pr[i2];
      float ga = pr[i1] / w, gb = pr[i2] / w;
      sel_e[2 * n] = i1; sel_e[2 * n + 1] = i2;
      sel_g[2 * n] = ga; sel_g[2 * n + 1] = gb;
      gsum[n] = ga + gb;
      s_i1 = i1; s_i2 = i2; s_g1 = ga; s_g2 = gb;
      atomicAdd(&f_acc[i1], 1.0f);
      atomicAdd(&f_acc[i2], 1.0f);
      for (int e = 0; e < E_; ++e) atomicAdd(&p_acc[e], pr[e]);
    }
    __syncthreads();
    int i1 = s_i1, i2 = s_i2; float ga = s_g1, gb = s_g2;
    for (int c = tid; c < C_; c += 256)
      K[(size_t)n * C_ + c] =
          ga * const2[i1 * C_ + c] + gb * const2[i2 * C_ + c];
  } else if (bid < N_ + 12) {
    // reduce rowmax partials: 3072 (e,c) entries
    int idx = (bid - N_) * 256 + tid;
    if (idx < E_ * C_) {
      float m = 0.f;
      #pragma unroll
      for (int t = 0; t < 24; ++t) m = fmaxf(m, rowmaxp[(size_t)idx * 24 + t]);
      rowmax[idx] = m;
    }
  } else {
    // thrmin[e] = min_o ( A!=0 ? -B/|A| : (B>=0 ? -inf : +inf) )
    float* red = sc;
    for (int e = 0; e < E_; ++e) {
      float m = INFINITY;
      for (int o = tid; o < HF_; o += 256) {
        float a = A[e * HF_ + o], b = Bc[e * HF_ + o];
        float thr = (a != 0.0f) ? (-b / fabsf(a))
                                : ((b >= 0.0f) ? -INFINITY : INFINITY);
        m = fminf(m, thr);
      }
      red[tid] = m;
      __syncthreads();
      for (int s = 128; s > 0; s >>= 1) {
        if (tid < s) red[tid] = fminf(red[tid], red[tid + s]);
        __syncthreads();
      }
      if (tid == 0) thrmin[e] = red[0];
      __syncthreads();
    }
  }
}

// ---------------------------------------------------------------------------
// K3: blocks [0,NROW): per (n,h) stage LEVELS slice (5.4 KB LDS, [w][c] bytes),
//     build spike lists for 28 (expert,w) tasks via byte compare level > e;
//     certified bound-prune; survivors into a global queue. Block 0 writes aux.
//     blocks [NROW, NROW+COMBB): streaming combine out = gsum*x + K.
// ---------------------------------------------------------------------------
__global__ __launch_bounds__(256) void k_lists(
    const float* __restrict__ x, const unsigned char* __restrict__ levels,
    const int* __restrict__ sel_e,
    const float* __restrict__ rowmax, const float* __restrict__ thrmin,
    unsigned short* __restrict__ list16,
    int* __restrict__ queue, int* __restrict__ qcount,
    const float* __restrict__ f_acc, const float* __restrict__ p_acc,
    float* __restrict__ aux_out,
    const float* __restrict__ gsum, const float* __restrict__ K,
    float* __restrict__ out) {
  __shared__ unsigned char xs8[14 * C_];   // [w][c], 5376 B
  int bid = blockIdx.x, tid = threadIdx.x;

  if (bid >= NROW) {
    // ---- combine blocks: thread per float4, coalesced ----
    int idx = (bid - NROW) * 256 + tid;         // over N*C*49 float4s
    int nc = idx / 49;                          // (n,c) row
    float g = gsum[nc / C_];
    float kc = K[nc];
    float4 v = ((const float4*)x)[idx];
    v.x = g * v.x + kc;
    v.y = g * v.y + kc;
    v.z = g * v.z + kc;
    v.w = g * v.w + kc;
    ((float4*)out)[idx] = v;
    return;
  }

  int lane = tid & 63, wave = tid >> 6;
  int n = bid / 14, h = bid - n * 14;
  unsigned long long lmask = (1ull << lane) - 1ull;

  if (bid == 0 && tid == 0) {
    float s = 0.f;
    for (int e = 0; e < E_; ++e)
      s += (f_acc[e] * (1.0f / N_)) * (p_acc[e] * (1.0f / N_));
    *aux_out = 0.01f * E_ * s;
  }

  // stage levels[n, :, h, :] -> xs8[w][c]   (7 ushort loads per c-row)
  for (int c = tid; c < C_; c += 256) {
    const unsigned short* p =
        (const unsigned short*)(levels + (size_t)(n * C_ + c) * HW_ + h * 14);
    #pragma unroll
    for (int i = 0; i < 7; ++i) {
      unsigned short u = p[i];
      xs8[(2 * i) * C_ + c]     = (unsigned char)(u & 0xff);
      xs8[(2 * i + 1) * C_ + c] = (unsigned char)(u >> 8);
    }
  }
  __syncthreads();

  for (int t = wave; t < 28; t += 4) {
    int k = t / 14, w = t - k * 14;
    int pair = 2 * n + k;
    int e = sel_e[pair];
    const float* rme = rowmax + e * C_;
    unsigned long long masks[6];
    int nnz = 0;
    float myb = 0.f;
    #pragma unroll
    for (int cb = 0; cb < 6; ++cb) {
      int c = cb * 64 + lane;
      bool sp = ((int)xs8[w * C_ + c] > e);     // level > e  <=>  spike
      unsigned long long m = __ballot(sp);
      masks[cb] = m;
      if (sp) myb += rme[c];
      nnz += __popcll(m);
    }
    // wave-sum the bound (uniform after butterfly)
    #pragma unroll
    for (int off = 1; off < 64; off <<= 1) myb += __shfl_xor(myb, off, 64);
    bool prune = (myb < thrmin[e] - 1e-4f);
    if (!prune) {
      int tw = pair * 196 + h * 14 + w;
      size_t lbase = (size_t)tw * LCAP;
      int cum = 0;
      #pragma unroll
      for (int cb = 0; cb < 6; ++cb) {
        unsigned long long m = masks[cb];
        bool sp = (m >> lane) & 1ull;
        int pos = cum + __popcll(m & lmask);
        if (sp && pos < LCAP) list16[lbase + pos] = (unsigned short)(cb * 64 + lane);
        cum += __popcll(m);
      }
      if (lane == 0) {
        int nv = nnz < LCAP ? nnz : LCAP;
        int qi = atomicAdd(qcount, 1);
        queue[qi] = tw | (nv << 20);
      }
    }
  }
}

// ---------------------------------------------------------------------------
// K4: gather — grid-stride over compacted queue; one wave per surviving task.
// 3 passes of 8 outputs/lane. Rare layer-2 spikes applied in-place by the wave.
// ---------------------------------------------------------------------------
__global__ __launch_bounds__(256, 4) void k_gather(
    const __hip_bfloat16* __restrict__ w1t,
    const float* __restrict__ A, const float* __restrict__ Bc,
    const int* __restrict__ sel_e, const float* __restrict__ sel_g,
    const int* __restrict__ queue, const int* __restrict__ qcount,
    const unsigned short* __restrict__ list16,
    const float* __restrict__ inv2v, const float* __restrict__ w2,
    float* __restrict__ out) {
  int nq = *qcount;
  int wid = blockIdx.x * 4 + (threadIdx.x >> 6);
  int lane = threadIdx.x & 63;
  int nwaves = gridDim.x * 4;

  for (int qi = wid; qi < nq; qi += nwaves) {
    int ent = queue[qi];
    int tw = ent & 0xFFFFF;
    int nnz = ent >> 20;
    int pair = tw / HW_, pos = tw - pair * HW_;
    int n = pair >> 1;
    int e = sel_e[pair];
    int lv = (int)list16[(size_t)tw * LCAP + lane];
    const uint4* wb = (const uint4*)(w1t + (size_t)e * C_ * HF_);  // 192 uint4/row

    #pragma unroll
    for (int pass = 0; pass < 3; ++pass) {
      const uint4* wbp = wb + pass * 64 + lane;
      float acc[8];
      #pragma unroll
      for (int q = 0; q < 8; ++q) acc[q] = 0.f;
      int j = 0;
      for (; j + 4 <= nnz; j += 4) {
        int c0 = __shfl(lv, j + 0);
        int c1 = __shfl(lv, j + 1);
        int c2 = __shfl(lv, j + 2);
        int c3 = __shfl(lv, j + 3);
        uint4 a = wbp[c0 * 192];
        uint4 b = wbp[c1 * 192];
        uint4 c = wbp[c2 * 192];
        uint4 d = wbp[c3 * 192];
        uint32_t ua[4] = {a.x, a.y, a.z, a.w};
        uint32_t ub[4] = {b.x, b.y, b.z, b.w};
        uint32_t uc[4] = {c.x, c.y, c.z, c.w};
        uint32_t ud[4] = {d.x, d.y, d.z, d.w};
        #pragma unroll
        for (int q = 0; q < 4; ++q) {
          acc[2 * q]     += __uint_as_float(ua[q] << 16) + __uint_as_float(ub[q] << 16) +
                            __uint_as_float(uc[q] << 16) + __uint_as_float(ud[q] << 16);
          acc[2 * q + 1] += __uint_as_float(ua[q] & 0xffff0000u) + __uint_as_float(ub[q] & 0xffff0000u) +
                            __uint_as_float(uc[q] & 0xffff0000u) + __uint_as_float(ud[q] & 0xffff0000u);
        }
      }
      for (; j < nnz; ++j) {
        int c0 = __shfl(lv, j);
        uint4 a = wbp[c0 * 192];
        uint32_t ua[4] = {a.x, a.y, a.z, a.w};
        #pragma unroll
        for (int q = 0; q < 4; ++q) {
          acc[2 * q]     += __uint_as_float(ua[q] << 16);
          acc[2 * q + 1] += __uint_as_float(ua[q] & 0xffff0000u);
        }
      }
      // threshold for my 8 outputs: o = (pass*64+lane)*8 + q
      int k2 = (pass * 64 + lane) * 2;
      float4 Av0 = ((const float4*)(A + e * HF_))[k2];
      float4 Av1 = ((const float4*)(A + e * HF_))[k2 + 1];
      float4 Bv0 = ((const float4*)(Bc + e * HF_))[k2];
      float4 Bv1 = ((const float4*)(Bc + e * HF_))[k2 + 1];
      float av[8] = {Av0.x, Av0.y, Av0.z, Av0.w, Av1.x, Av1.y, Av1.z, Av1.w};
      float bv[8] = {Bv0.x, Bv0.y, Bv0.z, Bv0.w, Bv1.x, Bv1.y, Bv1.z, Bv1.w};
      #pragma unroll
      for (int q = 0; q < 8; ++q) {
        unsigned long long fm = __ballot(av[q] * acc[q] + bv[q] >= 0.0f);
        while (fm) {                           // rare layer-2 spikes
          int b = __ffsll((unsigned long long)fm) - 1;
          fm &= fm - 1;
          int o = (pass * 64 + b) * 8 + q;
          float gk = sel_g[pair];
          const float* w2r = w2 + (size_t)e * C_ * HF_ + o;
          const float* ivr = inv2v + e * C_;
          for (int c = lane; c < C_; c += 64) {
            atomicAdd(&out[((size_t)(n * C_ + c)) * HW_ + pos],
                      gk * ivr[c] * w2r[(size_t)c * HF_]);
          }
        }
      }
    }
  }
}

// ---------------------------------------------------------------------------
// Workspace layout (bytes), total ~27 MB
// ---------------------------------------------------------------------------
extern "C" void kernel_launch(void* const* d_in, const int* in_sizes, int n_in,
                              void* d_out, int out_size, void* d_ws, size_t ws_size,
                              hipStream_t stream) {
  const float* x       = (const float*)d_in[0];
  const float* rw      = (const float*)d_in[1];
  const float* rb      = (const float*)d_in[2];
  const float* r_gamma = (const float*)d_in[3];
  const float* r_beta  = (const float*)d_in[4];
  const float* r_mean  = (const float*)d_in[5];
  const float* r_var   = (const float*)d_in[6];
  const float* w1      = (const float*)d_in[7];
  const float* b1      = (const float*)d_in[8];
  const float* g1      = (const float*)d_in[9];
  const float* be1     = (const float*)d_in[10];
  const float* m1      = (const float*)d_in[11];
  const float* v1      = (const float*)d_in[12];
  const float* w2      = (const float*)d_in[13];
  const float* b2      = (const float*)d_in[14];
  const float* g2      = (const float*)d_in[15];
  const float* be2     = (const float*)d_in[16];
  const float* m2      = (const float*)d_in[17];
  const float* v2      = (const float*)d_in[18];
  const float* taus    = (const float*)d_in[19];
  float* out = (float*)d_out;

  char* ws = (char*)d_ws;
  int*   header = (int*)ws;           // [1]=queue count
  float* f_acc  = (float*)ws + 8;
  float* p_acc  = (float*)ws + 16;
  float* cnt    = (float*)(ws + 256);
  int*   sel_e  = (int*)(ws + 196864);
  float* sel_g  = (float*)(ws + 197888);
  float* gsum   = (float*)(ws + 198912);
  float* K      = (float*)(ws + 199424);
  float* A      = (float*)(ws + 396032);
  float* Bc     = (float*)(ws + 445184);
  float* const2 = (float*)(ws + 494336);
  float* inv2v  = (float*)(ws + 506624);
  __hip_bfloat16* w1t = (__hip_bfloat16*)(ws + 715520);
  int*   queue  = (int*)(ws + 10152704);
  unsigned short* list16 = (unsigned short*)(ws + 10353408);
  float* rowmaxp = (float*)(ws + 16775936);
  float* rowmax  = (float*)(ws + 17070848);
  float* thrmin  = (float*)(ws + 17083136);
  unsigned char* levels = (unsigned char*)(ws + 17084416);  // 9633792 B
  int* qcount = header + 1;

  k_lifprep<<<LIFW + TRB + PRB, 256, 0, stream>>>(
      x, cnt, (unsigned int*)levels, w1, w1t,
      b1, g1, be1, m1, v1, b2, g2, be2, m2, v2, taus,
      A, Bc, const2, inv2v, rowmaxp, header);
  k_router<<<N_ + 13, 256, 0, stream>>>(
      cnt, rw, rb, r_gamma, r_beta, r_mean, r_var, const2,
      rowmaxp, rowmax, A, Bc, thrmin,
      sel_e, sel_g, gsum, K, f_acc, p_acc);
  k_lists<<<NROW + COMBB, 256, 0, stream>>>(
      x, levels, sel_e, rowmax, thrmin, list16, queue, qcount,
      f_acc, p_acc, out + (out_size - 1), gsum, K, out);
  k_gather<<<2048, 256, 0, stream>>>(
      w1t, A, Bc, sel_e, sel_g, queue, qcount, list16, inv2v, w2, out);
}